// Round 8
// baseline (1360.175 us; speedup 1.0000x reference)
//
#include <hip/hip_runtime.h>

typedef __attribute__((ext_vector_type(4))) float f32x4;
typedef __attribute__((ext_vector_type(8))) short s16x8;
typedef __attribute__((ext_vector_type(8))) _Float16 f16x8;

#define N_NODES 65536
#define GNPG 1024
#define FDIM 64
#define HDIM 128
#define KNN 16
#define JT 64      // knn j-tile
#define DSTR 68    // knn dist LDS row stride (f32)
#define SCAND 20   // per-subset candidate list (2 subsets/center)
#define NEDGE (N_NODES * KNN)

// Build MFMA B-fragment-ordered fp16 copy of W2 (128x128).
// Frag layout (16x16x32): lane l holds B[k = 8*(l>>4)+j + 32*ks][col = ct*16 + (l&15)], j=0..7.
__global__ void prep_weights_k(const float* __restrict__ W2, _Float16* __restrict__ w2f) {
  int tid = threadIdx.x;
  for (int idx = tid; idx < 8 * 4 * 64 * 8; idx += 256) {
    int j = idx & 7, l = (idx >> 3) & 63, ks = (idx >> 9) & 3, ct = idx >> 11;
    int k = 8 * (l >> 4) + j + 32 * ks, col = ct * 16 + (l & 15);
    w2f[idx] = (_Float16)W2[k * 128 + col];
  }
}

// Per-node precompute: f64 sq norm (+f32 copy) and fp16 copy of x (row-major = frag order).
__global__ void prep_node_k(const float* __restrict__ x, float* __restrict__ sq,
                            double* __restrict__ sq64, _Float16* __restrict__ xf) {
  int n = blockIdx.x * 256 + threadIdx.x;
  const f32x4* xp = (const f32x4*)(x + (size_t)n * FDIM);
  double s0 = 0, s1 = 0;
#pragma unroll
  for (int c8 = 0; c8 < 8; ++c8) {
    f32x4 a = xp[2 * c8], b = xp[2 * c8 + 1];
    f16x8 h;
#pragma unroll
    for (int e = 0; e < 4; ++e) {
      h[e] = (_Float16)a[e];
      h[4 + e] = (_Float16)b[e];
      s0 = fma((double)a[e], (double)a[e], s0);
      s1 = fma((double)b[e], (double)b[e], s1);
    }
    *(f16x8*)(xf + (size_t)n * FDIM + c8 * 8) = h;
  }
  double s = s0 + s1;
  sq64[n] = s;
  sq[n] = (float)s;
}

// Full-fp32 GEMM1: PQ[n][0:128] = x[n]@(W1_top - W1_bot); PQ[n][128:256] = x[n]@W1_bot + b1.
__global__ __launch_bounds__(256) void prep_pq_k(const float* __restrict__ x,
                                                 const float* __restrict__ W1,
                                                 const float* __restrict__ b1,
                                                 float* __restrict__ PQ) {
  __shared__ float WcL[64 * 256];   // 64KB
  __shared__ float xL[16 * 64];     // 4KB
  int tid = threadIdx.x;
  for (int i = tid; i < 64 * 256; i += 256) {
    int k = i >> 8, c = i & 255;
    WcL[i] = (c < 128) ? (W1[k * 128 + c] - W1[(k + 64) * 128 + c])
                       : W1[(k + 64) * 128 + (c - 128)];
  }
  int nbase = blockIdx.x * 16;
  for (int i = tid; i < 16 * 64; i += 256) xL[i] = x[(size_t)nbase * 64 + i];
  __syncthreads();
  int nl = tid >> 4, c0 = tid & 15;
  float acc[16];
#pragma unroll
  for (int j = 0; j < 16; ++j) acc[j] = 0.f;
  for (int k = 0; k < 64; ++k) {
    float xk = xL[nl * 64 + k];
    const float* wr = WcL + k * 256 + c0;
#pragma unroll
    for (int j = 0; j < 16; ++j) acc[j] = fmaf(xk, wr[16 * j], acc[j]);
  }
#pragma unroll
  for (int j = 0; j < 16; ++j) {
    int c = c0 + 16 * j;
    float b = (c >= 128) ? b1[c - 128] : 0.f;
    PQ[(size_t)(nbase + nl) * 256 + c] = acc[j] + b;
  }
}

// KNN stage 1 (fp16 MFMA): block = 128 centers of one graph. Per 64-col tile: stage fp16
// B-frags in LDS, 16 MFMA/wave, distances -> padded LDS, 2 threads/center scan 32 cols
// each keeping a register top-20 (sorted, strict-< insertion). fp16 noise << superset
// margin; knn2's f64 rescore is the correctness authority.
__global__ __launch_bounds__(256) void knn1_k(const _Float16* __restrict__ xf,
                                              const float* __restrict__ sq,
                                              unsigned short* __restrict__ candi) {
  __shared__ float sq_l[GNPG];
  __shared__ __attribute__((aligned(16))) _Float16 bfL[512 * 8];
  __shared__ __attribute__((aligned(16))) float distL[128 * DSTR];
  int tid = threadIdx.x, lane = tid & 63, wave = tid >> 6;
  int g = blockIdx.x >> 3;
  int rb = (blockIdx.x & 7) * 128;
  const _Float16* xfg = xf + (size_t)g * GNPG * FDIM;
  for (int i = tid; i < GNPG; i += 256) sq_l[i] = sq[g * GNPG + i];
  f16x8 af[2][2];
#pragma unroll
  for (int rt = 0; rt < 2; ++rt)
#pragma unroll
    for (int ks = 0; ks < 2; ++ks) {
      size_t off = (size_t)(rb + wave * 32 + rt * 16 + (lane & 15)) * FDIM + (lane >> 4) * 8 + 32 * ks;
      af[rt][ks] = *(const f16x8*)(xfg + off);
    }
  float dl[SCAND]; int il[SCAND];
#pragma unroll
  for (int q = 0; q < SCAND; ++q) { dl[q] = 3.0e38f; il[q] = 0; }
  int c = tid >> 1, sub = tid & 1;
  for (int jt = 0; jt < GNPG / JT; ++jt) {
#pragma unroll
    for (int s2 = tid; s2 < 512; s2 += 256) {
      int ct = s2 >> 7, ks = (s2 >> 6) & 1, l = s2 & 63;
      size_t goff = (size_t)(jt * JT + ct * 16 + (l & 15)) * FDIM + (l >> 4) * 8 + 32 * ks;
      *(f16x8*)(bfL + s2 * 8) = *(const f16x8*)(xfg + goff);
    }
    __syncthreads();
    f32x4 acc[2][4];
#pragma unroll
    for (int rt = 0; rt < 2; ++rt)
#pragma unroll
      for (int ct = 0; ct < 4; ++ct) acc[rt][ct] = (f32x4){0.f, 0.f, 0.f, 0.f};
#pragma unroll
    for (int ks = 0; ks < 2; ++ks)
#pragma unroll
      for (int ct = 0; ct < 4; ++ct) {
        f16x8 bfr = *(const f16x8*)(bfL + ((ct * 2 + ks) * 64 + lane) * 8);
#pragma unroll
        for (int rt = 0; rt < 2; ++rt)
          acc[rt][ct] = __builtin_amdgcn_mfma_f32_16x16x32_f16(af[rt][ks], bfr, acc[rt][ct], 0, 0, 0);
      }
#pragma unroll
    for (int rt = 0; rt < 2; ++rt)
#pragma unroll
      for (int ct = 0; ct < 4; ++ct) {
        int coltl = ct * 16 + (lane & 15);
        int jlg = jt * JT + coltl;
        float sqj = sq_l[jlg];
#pragma unroll
        for (int r = 0; r < 4; ++r) {
          int row = wave * 32 + rt * 16 + (lane >> 4) * 4 + r;
          float d = sq_l[rb + row] + sqj - 2.f * acc[rt][ct][r];
          if (rb + row == jlg) d = 3.0e38f;
          distL[row * DSTR + coltl] = d;
        }
      }
    __syncthreads();
#pragma unroll 2
    for (int i = 0; i < 8; ++i) {
      f32x4 v = *(const f32x4*)(distL + c * DSTR + sub * 32 + i * 4);
#pragma unroll
      for (int e = 0; e < 4; ++e) {
        float d = v[e];
        if (d < dl[SCAND - 1]) {
          dl[SCAND - 1] = d; il[SCAND - 1] = jt * JT + sub * 32 + i * 4 + e;
#pragma unroll
          for (int p = SCAND - 1; p >= 1; --p) {
            float a0 = dl[p - 1], a1 = dl[p];
            int b0 = il[p - 1], b1v = il[p];
            bool cc = a1 < a0;
            dl[p - 1] = cc ? a1 : a0; dl[p] = cc ? a0 : a1;
            il[p - 1] = cc ? b1v : b0; il[p] = cc ? b0 : b1v;
          }
        }
      }
    }
  }
  int nglob = g * GNPG + rb + c;
  unsigned short* ii = candi + (size_t)nglob * (2 * SCAND) + sub * SCAND;
#pragma unroll
  for (int q = 0; q < SCAND; ++q) ii[q] = (unsigned short)il[q];
}

// KNN stage 2: 2 threads per center. Each thread rescores its own sub's 20 candidates in
// exact f64, selection-sorts top-16 by (d64, idx), dumps to LDS; sub-0 2-pointer-merges
// the two sorted 16-lists -> nbr + counts. No f32 merge phase, no spill-scale state.
__global__ __launch_bounds__(256) void knn2_k(const float* __restrict__ x,
                                              const double* __restrict__ sq64,
                                              const unsigned short* __restrict__ candi,
                                              int* __restrict__ nbr, int* __restrict__ counts) {
  __shared__ double md[2][128][17];
  __shared__ unsigned short mi[2][128][17];
  int tid = threadIdx.x;
  int c_local = tid >> 1, sub = tid & 1;
  int n = blockIdx.x * 128 + c_local;
  int gbase = n & ~(GNPG - 1);
  int il[SCAND];
  const unsigned short* ii = candi + (size_t)n * (2 * SCAND) + sub * SCAND;
#pragma unroll
  for (int q = 0; q < SCAND; ++q) il[q] = ii[q];
  f32x4 xi[16];
  const f32x4* xp = (const f32x4*)(x + (size_t)n * FDIM);
#pragma unroll
  for (int f = 0; f < 16; ++f) xi[f] = xp[f];
  double d64[SCAND];
  double sq64i = sq64[n];
#pragma unroll
  for (int q = 0; q < SCAND; ++q) {
    int j = gbase + il[q];
    const f32x4* xj = (const f32x4*)(x + (size_t)j * FDIM);
    double t0 = 0, t1 = 0, t2 = 0, t3 = 0;
#pragma unroll
    for (int f = 0; f < 16; ++f) {
      f32x4 a = xi[f], b = xj[f];
      t0 = fma((double)a[0], (double)b[0], t0);
      t1 = fma((double)a[1], (double)b[1], t1);
      t2 = fma((double)a[2], (double)b[2], t2);
      t3 = fma((double)a[3], (double)b[3], t3);
    }
    d64[q] = sq64i + sq64[j] - 2.0 * ((t0 + t1) + (t2 + t3));
  }
  // Selection sort: first 16 positions by (d64, idx).
#pragma unroll
  for (int a = 0; a < KNN; ++a)
#pragma unroll
    for (int b = a + 1; b < SCAND; ++b) {
      bool sw = (d64[b] < d64[a]) || (d64[b] == d64[a] && il[b] < il[a]);
      double td = sw ? d64[b] : d64[a];
      double tu = sw ? d64[a] : d64[b];
      int ti = sw ? il[b] : il[a];
      int tv = sw ? il[a] : il[b];
      d64[a] = td; d64[b] = tu; il[a] = ti; il[b] = tv;
    }
#pragma unroll
  for (int q = 0; q < KNN; ++q) {
    md[sub][c_local][q] = d64[q];
    mi[sub][c_local][q] = (unsigned short)il[q];
  }
  __syncthreads();
  if (sub == 0) {
    int pa = 0, pb = 0;
    for (int q = 0; q < KNN; ++q) {
      double da = md[0][c_local][pa]; int ia = mi[0][c_local][pa];
      double db = md[1][c_local][pb]; int ib = mi[1][c_local][pb];
      bool tb = (db < da) || (db == da && ib < ia);
      int iw = tb ? ib : ia;
      pa += !tb; pb += tb;
      int gidx = gbase + iw;
      nbr[(size_t)n * KNN + q] = gidx;
      atomicAdd(&counts[gidx], 1);
    }
  }
}

__global__ void scan_k(const int* __restrict__ counts, int* __restrict__ cursor) {
  __shared__ int part[256];
  int t = threadIdx.x, base = t * 256;
  int s = 0;
  for (int i = 0; i < 256; ++i) s += counts[base + i];
  part[t] = s;
  __syncthreads();
  if (t == 0) {
    int run = 0;
    for (int i = 0; i < 256; ++i) { int v = part[i]; part[i] = run; run += v; }
  }
  __syncthreads();
  int run = part[t];
  for (int i = 0; i < 256; ++i) { int idx = base + i; cursor[idx] = run; run += counts[idx]; }
}

__global__ void scatter_k(const int* __restrict__ nbr, int* __restrict__ cursor,
                          int* __restrict__ srow, int* __restrict__ scol) {
  int e = blockIdx.x * 256 + threadIdx.x;
  int r = nbr[e], c = e >> 4;
  int pos = atomicAdd(&cursor[r], 1);
  srow[pos] = r; scol[pos] = c;
}

// Per 64-edge tile: h1 = relu(P[row]+Q'[col]) fp32 -> fp16 -> swizzled LDS (16KB);
// fp16 MFMA vs W2 frags; relu(+b2) -> swizzled LDS f32 (32KB, aliases A after barrier);
// segmented sum by sorted row -> atomicAdd. 32KB LDS -> ~3 blocks/CU.
__global__ __launch_bounds__(256) void gemm2_k(const float* __restrict__ PQ,
                                               const int* __restrict__ srow, const int* __restrict__ scol,
                                               const _Float16* __restrict__ w2f,
                                               const float* __restrict__ b2,
                                               float* __restrict__ out) {
  __shared__ __attribute__((aligned(16))) char smem[32768];
  float* h2 = (float*)smem;
  int tid = threadIdx.x, lane = tid & 63, wave = tid >> 6;
  int cg = wave & 1, eg = wave >> 1;
  f16x8 wf[4][4];
#pragma unroll
  for (int ct = 0; ct < 4; ++ct)
#pragma unroll
    for (int ks = 0; ks < 4; ++ks)
      wf[ct][ks] = *(const f16x8*)(w2f + ((((cg * 4 + ct) * 4 + ks) * 64 + lane) * 8));
  float b2r[4];
#pragma unroll
  for (int ct = 0; ct < 4; ++ct) b2r[ct] = b2[cg * 64 + ct * 16 + (lane & 15)];

  for (int tile = blockIdx.x; tile < NEDGE / 64; tile += gridDim.x) {
    int base = tile * 64;
    {
      int e_in = tid >> 2, qq = tid & 3;
      int e = base + e_in;
      int row = srow[e], colc = scol[e];
      const float* Pp = PQ + (size_t)row * 256 + qq * 32;
      const float* Qp = PQ + (size_t)colc * 256 + 128 + qq * 32;
#pragma unroll
      for (int c8 = 0; c8 < 4; ++c8) {
        f32x4 p0 = *(const f32x4*)(Pp + c8 * 8);
        f32x4 p1 = *(const f32x4*)(Pp + c8 * 8 + 4);
        f32x4 q0 = *(const f32x4*)(Qp + c8 * 8);
        f32x4 q1 = *(const f32x4*)(Qp + c8 * 8 + 4);
        f16x8 hv;
#pragma unroll
        for (int k2 = 0; k2 < 4; ++k2) {
          float sv = p0[k2] + q0[k2];
          hv[k2] = (_Float16)(sv > 0.f ? sv : 0.f);
          float sw = p1[k2] + q1[k2];
          hv[4 + k2] = (_Float16)(sw > 0.f ? sw : 0.f);
        }
        int byteoff = e_in * 256 + ((2 * (qq * 32 + c8 * 8)) ^ ((e_in & 7) << 4));
        *(f16x8*)(smem + byteoff) = hv;
      }
    }
    __syncthreads();
    f32x4 acc[2][4];
#pragma unroll
    for (int rt = 0; rt < 2; ++rt)
#pragma unroll
      for (int ct = 0; ct < 4; ++ct) acc[rt][ct] = (f32x4){0.f, 0.f, 0.f, 0.f};
#pragma unroll
    for (int rt = 0; rt < 2; ++rt) {
      int rowL = eg * 32 + rt * 16 + (lane & 15);
#pragma unroll
      for (int ks = 0; ks < 4; ++ks) {
        int byteoff = rowL * 256 + ((16 * (lane >> 4) + 64 * ks) ^ ((rowL & 7) << 4));
        f16x8 a = *(const f16x8*)(smem + byteoff);
#pragma unroll
        for (int ct = 0; ct < 4; ++ct)
          acc[rt][ct] = __builtin_amdgcn_mfma_f32_16x16x32_f16(a, wf[ct][ks], acc[rt][ct], 0, 0, 0);
      }
    }
    __syncthreads();
#pragma unroll
    for (int rt = 0; rt < 2; ++rt)
#pragma unroll
      for (int ct = 0; ct < 4; ++ct) {
        int col = cg * 64 + ct * 16 + (lane & 15);
#pragma unroll
        for (int r = 0; r < 4; ++r) {
          int row_in = eg * 32 + rt * 16 + (lane >> 4) * 4 + r;
          float v = acc[rt][ct][r] + b2r[ct];
          v = v > 0.f ? v : 0.f;
          int gq = (row_in >> 2) & 3;
          h2[row_in * 128 + (col ^ (gq << 2) ^ ((gq & 1) << 4))] = v;
        }
      }
    __syncthreads();
    {
      int col = tid & 127, estart = (tid >> 7) * 32;
      float a = 0.f;
      int prev = srow[base + estart];
#pragma unroll 8
      for (int e2 = estart; e2 < estart + 32; ++e2) {
        int r2 = srow[base + e2];
        if (r2 != prev) { atomicAdd(out + (size_t)prev * 128 + col, a); a = 0.f; prev = r2; }
        int gq = (e2 >> 2) & 3;
        a += h2[e2 * 128 + (col ^ (gq << 2) ^ ((gq & 1) << 4))];
      }
      atomicAdd(out + (size_t)prev * 128 + col, a);
    }
    __syncthreads();
  }
}

__global__ void final_k(float* __restrict__ out, const int* __restrict__ counts) {
  int idx = blockIdx.x * 256 + threadIdx.x;
  int n = idx >> 7;
  int c = counts[n];
  c = c > 0 ? c : 1;
  out[idx] = out[idx] / (float)c;
}

extern "C" void kernel_launch(void* const* d_in, const int* in_sizes, int n_in,
                              void* d_out, int out_size, void* d_ws, size_t ws_size,
                              hipStream_t stream) {
  const float* x = (const float*)d_in[0];
  const float* W1 = (const float*)d_in[2];
  const float* b1 = (const float*)d_in[3];
  const float* W2 = (const float*)d_in[4];
  const float* b2 = (const float*)d_in[5];
  float* out = (float*)d_out;
  char* ws = (char*)d_ws;

  // PQ region (64 MB) is aliased by KNN-phase buffers (candi/xf): all KNN kernels run
  // BEFORE prep_pq_k writes PQ, so lifetimes are disjoint (stream-ordered).
  float* PQ = (float*)(ws + 0);                            // 67,108,864 B
  unsigned short* candi = (unsigned short*)(ws + 0);       //  5,242,880 B (alias PQ)
  _Float16* xf = (_Float16*)(ws + 16777216);               //  8,388,608 B (alias PQ)
  float* sq = (float*)(ws + 67108864);                     //    262,144 B
  int* nbr = (int*)(ws + 67371008);                        //  4,194,304 B
  int* counts = (int*)(ws + 71565312);                     //    262,144 B
  int* cursor = (int*)(ws + 71827456);                     //    262,144 B
  int* srow = (int*)(ws + 72089600);                       //  4,194,304 B
  int* scol = (int*)(ws + 76283904);                       //  4,194,304 B
  _Float16* w2f = (_Float16*)(ws + 80478208);              //     32,768 B
  double* sq64 = (double*)(ws + 80543744);                 //    524,288 B  (end 81,068,032)

  hipMemsetAsync(d_out, 0, (size_t)out_size * sizeof(float), stream);
  hipMemsetAsync(counts, 0, (size_t)N_NODES * sizeof(int), stream);
  prep_weights_k<<<1, 256, 0, stream>>>(W2, w2f);
  prep_node_k<<<N_NODES / 256, 256, 0, stream>>>(x, sq, sq64, xf);
  knn1_k<<<N_NODES / 128, 256, 0, stream>>>(xf, sq, candi);
  knn2_k<<<N_NODES / 128, 256, 0, stream>>>(x, sq64, candi, nbr, counts);
  scan_k<<<1, 256, 0, stream>>>(counts, cursor);
  scatter_k<<<NEDGE / 256, 256, 0, stream>>>(nbr, cursor, srow, scol);
  prep_pq_k<<<N_NODES / 16, 256, 0, stream>>>(x, W1, b1, PQ);
  gemm2_k<<<2048, 256, 0, stream>>>(PQ, srow, scol, w2f, b2, out);
  final_k<<<(N_NODES * HDIM) / 256, 256, 0, stream>>>(out, counts);
}

// Round 9
// 967.515 us; speedup vs baseline: 1.4058x; 1.4058x over previous
//
#include <hip/hip_runtime.h>

typedef __attribute__((ext_vector_type(4))) float f32x4;
typedef __attribute__((ext_vector_type(8))) short s16x8;
typedef __attribute__((ext_vector_type(8))) _Float16 f16x8;

#define N_NODES 65536
#define GNPG 1024
#define FDIM 64
#define HDIM 128
#define KNN 16
#define JT 64      // knn j-tile
#define DSTR 68    // knn dist LDS row stride (f32)
#define SCAND 20   // per-subset candidate list (2 subsets/center)
#define NEDGE (N_NODES * KNN)

// Build MFMA B-fragment-ordered fp16 copy of W2 (128x128).
// Frag layout (16x16x32): lane l holds B[k = 8*(l>>4)+j + 32*ks][col = ct*16 + (l&15)], j=0..7.
__global__ void prep_weights_k(const float* __restrict__ W2, _Float16* __restrict__ w2f) {
  int tid = threadIdx.x;
  for (int idx = tid; idx < 8 * 4 * 64 * 8; idx += 256) {
    int j = idx & 7, l = (idx >> 3) & 63, ks = (idx >> 9) & 3, ct = idx >> 11;
    int k = 8 * (l >> 4) + j + 32 * ks, col = ct * 16 + (l & 15);
    w2f[idx] = (_Float16)W2[k * 128 + col];
  }
}

// Per-node precompute: f64 sq norm (+f32 copy) and fp16 copy of x (row-major = frag order).
__global__ void prep_node_k(const float* __restrict__ x, float* __restrict__ sq,
                            double* __restrict__ sq64, _Float16* __restrict__ xf) {
  int n = blockIdx.x * 256 + threadIdx.x;
  const f32x4* xp = (const f32x4*)(x + (size_t)n * FDIM);
  double s0 = 0, s1 = 0;
#pragma unroll
  for (int c8 = 0; c8 < 8; ++c8) {
    f32x4 a = xp[2 * c8], b = xp[2 * c8 + 1];
    f16x8 h;
#pragma unroll
    for (int e = 0; e < 4; ++e) {
      h[e] = (_Float16)a[e];
      h[4 + e] = (_Float16)b[e];
      s0 = fma((double)a[e], (double)a[e], s0);
      s1 = fma((double)b[e], (double)b[e], s1);
    }
    *(f16x8*)(xf + (size_t)n * FDIM + c8 * 8) = h;
  }
  double s = s0 + s1;
  sq64[n] = s;
  sq[n] = (float)s;
}

// Full-fp32 GEMM1: PQ[n][0:128] = x[n]@(W1_top - W1_bot); PQ[n][128:256] = x[n]@W1_bot + b1.
__global__ __launch_bounds__(256) void prep_pq_k(const float* __restrict__ x,
                                                 const float* __restrict__ W1,
                                                 const float* __restrict__ b1,
                                                 float* __restrict__ PQ) {
  __shared__ float WcL[64 * 256];   // 64KB
  __shared__ float xL[16 * 64];     // 4KB
  int tid = threadIdx.x;
  for (int i = tid; i < 64 * 256; i += 256) {
    int k = i >> 8, c = i & 255;
    WcL[i] = (c < 128) ? (W1[k * 128 + c] - W1[(k + 64) * 128 + c])
                       : W1[(k + 64) * 128 + (c - 128)];
  }
  int nbase = blockIdx.x * 16;
  for (int i = tid; i < 16 * 64; i += 256) xL[i] = x[(size_t)nbase * 64 + i];
  __syncthreads();
  int nl = tid >> 4, c0 = tid & 15;
  float acc[16];
#pragma unroll
  for (int j = 0; j < 16; ++j) acc[j] = 0.f;
  for (int k = 0; k < 64; ++k) {
    float xk = xL[nl * 64 + k];
    const float* wr = WcL + k * 256 + c0;
#pragma unroll
    for (int j = 0; j < 16; ++j) acc[j] = fmaf(xk, wr[16 * j], acc[j]);
  }
#pragma unroll
  for (int j = 0; j < 16; ++j) {
    int c = c0 + 16 * j;
    float b = (c >= 128) ? b1[c - 128] : 0.f;
    PQ[(size_t)(nbase + nl) * 256 + c] = acc[j] + b;
  }
}

// KNN stage 1 (fp16 MFMA): block = 128 centers of one graph. Per 64-col tile: stage fp16
// B-frags in LDS, 16 MFMA/wave, distances -> padded LDS, 2 threads/center scan 32 cols
// each keeping a register top-20 (sorted, strict-< insertion). fp16 noise << superset
// margin; knn2's f64 rescore is the correctness authority.
__global__ __launch_bounds__(256) void knn1_k(const _Float16* __restrict__ xf,
                                              const float* __restrict__ sq,
                                              unsigned short* __restrict__ candi) {
  __shared__ float sq_l[GNPG];
  __shared__ __attribute__((aligned(16))) _Float16 bfL[512 * 8];
  __shared__ __attribute__((aligned(16))) float distL[128 * DSTR];
  int tid = threadIdx.x, lane = tid & 63, wave = tid >> 6;
  int g = blockIdx.x >> 3;
  int rb = (blockIdx.x & 7) * 128;
  const _Float16* xfg = xf + (size_t)g * GNPG * FDIM;
  for (int i = tid; i < GNPG; i += 256) sq_l[i] = sq[g * GNPG + i];
  f16x8 af[2][2];
#pragma unroll
  for (int rt = 0; rt < 2; ++rt)
#pragma unroll
    for (int ks = 0; ks < 2; ++ks) {
      size_t off = (size_t)(rb + wave * 32 + rt * 16 + (lane & 15)) * FDIM + (lane >> 4) * 8 + 32 * ks;
      af[rt][ks] = *(const f16x8*)(xfg + off);
    }
  float dl[SCAND]; int il[SCAND];
#pragma unroll
  for (int q = 0; q < SCAND; ++q) { dl[q] = 3.0e38f; il[q] = 0; }
  int c = tid >> 1, sub = tid & 1;
  for (int jt = 0; jt < GNPG / JT; ++jt) {
#pragma unroll
    for (int s2 = tid; s2 < 512; s2 += 256) {
      int ct = s2 >> 7, ks = (s2 >> 6) & 1, l = s2 & 63;
      size_t goff = (size_t)(jt * JT + ct * 16 + (l & 15)) * FDIM + (l >> 4) * 8 + 32 * ks;
      *(f16x8*)(bfL + s2 * 8) = *(const f16x8*)(xfg + goff);
    }
    __syncthreads();
    f32x4 acc[2][4];
#pragma unroll
    for (int rt = 0; rt < 2; ++rt)
#pragma unroll
      for (int ct = 0; ct < 4; ++ct) acc[rt][ct] = (f32x4){0.f, 0.f, 0.f, 0.f};
#pragma unroll
    for (int ks = 0; ks < 2; ++ks)
#pragma unroll
      for (int ct = 0; ct < 4; ++ct) {
        f16x8 bfr = *(const f16x8*)(bfL + ((ct * 2 + ks) * 64 + lane) * 8);
#pragma unroll
        for (int rt = 0; rt < 2; ++rt)
          acc[rt][ct] = __builtin_amdgcn_mfma_f32_16x16x32_f16(af[rt][ks], bfr, acc[rt][ct], 0, 0, 0);
      }
#pragma unroll
    for (int rt = 0; rt < 2; ++rt)
#pragma unroll
      for (int ct = 0; ct < 4; ++ct) {
        int coltl = ct * 16 + (lane & 15);
        int jlg = jt * JT + coltl;
        float sqj = sq_l[jlg];
#pragma unroll
        for (int r = 0; r < 4; ++r) {
          int row = wave * 32 + rt * 16 + (lane >> 4) * 4 + r;
          float d = sq_l[rb + row] + sqj - 2.f * acc[rt][ct][r];
          if (rb + row == jlg) d = 3.0e38f;
          distL[row * DSTR + coltl] = d;
        }
      }
    __syncthreads();
#pragma unroll 2
    for (int i = 0; i < 8; ++i) {
      f32x4 v = *(const f32x4*)(distL + c * DSTR + sub * 32 + i * 4);
#pragma unroll
      for (int e = 0; e < 4; ++e) {
        float d = v[e];
        if (d < dl[SCAND - 1]) {
          dl[SCAND - 1] = d; il[SCAND - 1] = jt * JT + sub * 32 + i * 4 + e;
#pragma unroll
          for (int p = SCAND - 1; p >= 1; --p) {
            float a0 = dl[p - 1], a1 = dl[p];
            int b0 = il[p - 1], b1v = il[p];
            bool cc = a1 < a0;
            dl[p - 1] = cc ? a1 : a0; dl[p] = cc ? a0 : a1;
            il[p - 1] = cc ? b1v : b0; il[p] = cc ? b0 : b1v;
          }
        }
      }
    }
  }
  int nglob = g * GNPG + rb + c;
  unsigned short* ii = candi + (size_t)nglob * (2 * SCAND) + sub * SCAND;
#pragma unroll
  for (int q = 0; q < SCAND; ++q) ii[q] = (unsigned short)il[q];
}

// KNN stage 2: 1 thread/center, knn1-shaped structure: NON-unrolled loop over all 40
// candidates (loads consumed immediately -> no register blowup), exact f64 distance,
// compile-time-unrolled insertion into a 16-deep (d64, idx)-sorted register list.
// The two subs' candidate sets are disjoint; f64 values exact -> list = f64 top-16.
__global__ __launch_bounds__(256) void knn2_k(const float* __restrict__ x,
                                              const double* __restrict__ sq64,
                                              const unsigned short* __restrict__ candi,
                                              int* __restrict__ nbr, int* __restrict__ counts) {
  int n = blockIdx.x * 256 + threadIdx.x;
  int gbase = n & ~(GNPG - 1);
  f32x4 xi[16];
  const f32x4* xp = (const f32x4*)(x + (size_t)n * FDIM);
#pragma unroll
  for (int f = 0; f < 16; ++f) xi[f] = xp[f];
  double sq64i = sq64[n];
  double dl[KNN]; int il[KNN];
#pragma unroll
  for (int q = 0; q < KNN; ++q) { dl[q] = 1.0e300; il[q] = 0x7FFFFFFF; }
  const unsigned short* ii = candi + (size_t)n * (2 * SCAND);
#pragma unroll 1
  for (int t = 0; t < 2 * SCAND; ++t) {
    int jl = ii[t];
    int j = gbase + jl;
    const f32x4* xj = (const f32x4*)(x + (size_t)j * FDIM);
    double t0 = 0, t1 = 0, t2 = 0, t3 = 0;
#pragma unroll
    for (int f = 0; f < 16; ++f) {
      f32x4 a = xi[f], b = xj[f];
      t0 = fma((double)a[0], (double)b[0], t0);
      t1 = fma((double)a[1], (double)b[1], t1);
      t2 = fma((double)a[2], (double)b[2], t2);
      t3 = fma((double)a[3], (double)b[3], t3);
    }
    double d = sq64i + sq64[j] - 2.0 * ((t0 + t1) + (t2 + t3));
    bool ins = (d < dl[KNN - 1]) || (d == dl[KNN - 1] && jl < il[KNN - 1]);
    if (ins) {
      dl[KNN - 1] = d; il[KNN - 1] = jl;
#pragma unroll
      for (int p = KNN - 1; p >= 1; --p) {
        double a0 = dl[p - 1], a1 = dl[p];
        int b0 = il[p - 1], b1v = il[p];
        bool cc = (a1 < a0) || (a1 == a0 && b1v < b0);
        dl[p - 1] = cc ? a1 : a0; dl[p] = cc ? a0 : a1;
        il[p - 1] = cc ? b1v : b0; il[p] = cc ? b0 : b1v;
      }
    }
  }
#pragma unroll
  for (int q = 0; q < KNN; ++q) {
    int gidx = gbase + il[q];
    nbr[(size_t)n * KNN + q] = gidx;
    atomicAdd(&counts[gidx], 1);
  }
}

__global__ void scan_k(const int* __restrict__ counts, int* __restrict__ cursor) {
  __shared__ int part[256];
  int t = threadIdx.x, base = t * 256;
  int s = 0;
  for (int i = 0; i < 256; ++i) s += counts[base + i];
  part[t] = s;
  __syncthreads();
  if (t == 0) {
    int run = 0;
    for (int i = 0; i < 256; ++i) { int v = part[i]; part[i] = run; run += v; }
  }
  __syncthreads();
  int run = part[t];
  for (int i = 0; i < 256; ++i) { int idx = base + i; cursor[idx] = run; run += counts[idx]; }
}

__global__ void scatter_k(const int* __restrict__ nbr, int* __restrict__ cursor,
                          int* __restrict__ srow, int* __restrict__ scol) {
  int e = blockIdx.x * 256 + threadIdx.x;
  int r = nbr[e], c = e >> 4;
  int pos = atomicAdd(&cursor[r], 1);
  srow[pos] = r; scol[pos] = c;
}

// Per 64-edge tile: h1 = relu(P[row]+Q'[col]) fp32 -> fp16 -> swizzled LDS (16KB);
// fp16 MFMA vs W2 frags; relu(+b2) -> swizzled LDS f32 (32KB, aliases A after barrier);
// segmented sum by sorted row -> atomicAdd. 32KB LDS -> ~3 blocks/CU.
__global__ __launch_bounds__(256) void gemm2_k(const float* __restrict__ PQ,
                                               const int* __restrict__ srow, const int* __restrict__ scol,
                                               const _Float16* __restrict__ w2f,
                                               const float* __restrict__ b2,
                                               float* __restrict__ out) {
  __shared__ __attribute__((aligned(16))) char smem[32768];
  float* h2 = (float*)smem;
  int tid = threadIdx.x, lane = tid & 63, wave = tid >> 6;
  int cg = wave & 1, eg = wave >> 1;
  f16x8 wf[4][4];
#pragma unroll
  for (int ct = 0; ct < 4; ++ct)
#pragma unroll
    for (int ks = 0; ks < 4; ++ks)
      wf[ct][ks] = *(const f16x8*)(w2f + ((((cg * 4 + ct) * 4 + ks) * 64 + lane) * 8));
  float b2r[4];
#pragma unroll
  for (int ct = 0; ct < 4; ++ct) b2r[ct] = b2[cg * 64 + ct * 16 + (lane & 15)];

  for (int tile = blockIdx.x; tile < NEDGE / 64; tile += gridDim.x) {
    int base = tile * 64;
    {
      int e_in = tid >> 2, qq = tid & 3;
      int e = base + e_in;
      int row = srow[e], colc = scol[e];
      const float* Pp = PQ + (size_t)row * 256 + qq * 32;
      const float* Qp = PQ + (size_t)colc * 256 + 128 + qq * 32;
#pragma unroll
      for (int c8 = 0; c8 < 4; ++c8) {
        f32x4 p0 = *(const f32x4*)(Pp + c8 * 8);
        f32x4 p1 = *(const f32x4*)(Pp + c8 * 8 + 4);
        f32x4 q0 = *(const f32x4*)(Qp + c8 * 8);
        f32x4 q1 = *(const f32x4*)(Qp + c8 * 8 + 4);
        f16x8 hv;
#pragma unroll
        for (int k2 = 0; k2 < 4; ++k2) {
          float sv = p0[k2] + q0[k2];
          hv[k2] = (_Float16)(sv > 0.f ? sv : 0.f);
          float sw = p1[k2] + q1[k2];
          hv[4 + k2] = (_Float16)(sw > 0.f ? sw : 0.f);
        }
        int byteoff = e_in * 256 + ((2 * (qq * 32 + c8 * 8)) ^ ((e_in & 7) << 4));
        *(f16x8*)(smem + byteoff) = hv;
      }
    }
    __syncthreads();
    f32x4 acc[2][4];
#pragma unroll
    for (int rt = 0; rt < 2; ++rt)
#pragma unroll
      for (int ct = 0; ct < 4; ++ct) acc[rt][ct] = (f32x4){0.f, 0.f, 0.f, 0.f};
#pragma unroll
    for (int rt = 0; rt < 2; ++rt) {
      int rowL = eg * 32 + rt * 16 + (lane & 15);
#pragma unroll
      for (int ks = 0; ks < 4; ++ks) {
        int byteoff = rowL * 256 + ((16 * (lane >> 4) + 64 * ks) ^ ((rowL & 7) << 4));
        f16x8 a = *(const f16x8*)(smem + byteoff);
#pragma unroll
        for (int ct = 0; ct < 4; ++ct)
          acc[rt][ct] = __builtin_amdgcn_mfma_f32_16x16x32_f16(a, wf[ct][ks], acc[rt][ct], 0, 0, 0);
      }
    }
    __syncthreads();
#pragma unroll
    for (int rt = 0; rt < 2; ++rt)
#pragma unroll
      for (int ct = 0; ct < 4; ++ct) {
        int col = cg * 64 + ct * 16 + (lane & 15);
#pragma unroll
        for (int r = 0; r < 4; ++r) {
          int row_in = eg * 32 + rt * 16 + (lane >> 4) * 4 + r;
          float v = acc[rt][ct][r] + b2r[ct];
          v = v > 0.f ? v : 0.f;
          int gq = (row_in >> 2) & 3;
          h2[row_in * 128 + (col ^ (gq << 2) ^ ((gq & 1) << 4))] = v;
        }
      }
    __syncthreads();
    {
      int col = tid & 127, estart = (tid >> 7) * 32;
      float a = 0.f;
      int prev = srow[base + estart];
#pragma unroll 8
      for (int e2 = estart; e2 < estart + 32; ++e2) {
        int r2 = srow[base + e2];
        if (r2 != prev) { atomicAdd(out + (size_t)prev * 128 + col, a); a = 0.f; prev = r2; }
        int gq = (e2 >> 2) & 3;
        a += h2[e2 * 128 + (col ^ (gq << 2) ^ ((gq & 1) << 4))];
      }
      atomicAdd(out + (size_t)prev * 128 + col, a);
    }
    __syncthreads();
  }
}

__global__ void final_k(float* __restrict__ out, const int* __restrict__ counts) {
  int idx = blockIdx.x * 256 + threadIdx.x;
  int n = idx >> 7;
  int c = counts[n];
  c = c > 0 ? c : 1;
  out[idx] = out[idx] / (float)c;
}

extern "C" void kernel_launch(void* const* d_in, const int* in_sizes, int n_in,
                              void* d_out, int out_size, void* d_ws, size_t ws_size,
                              hipStream_t stream) {
  const float* x = (const float*)d_in[0];
  const float* W1 = (const float*)d_in[2];
  const float* b1 = (const float*)d_in[3];
  const float* W2 = (const float*)d_in[4];
  const float* b2 = (const float*)d_in[5];
  float* out = (float*)d_out;
  char* ws = (char*)d_ws;

  // PQ region (64 MB) is aliased by KNN-phase buffers (candi/xf): all KNN kernels run
  // BEFORE prep_pq_k writes PQ, so lifetimes are disjoint (stream-ordered).
  float* PQ = (float*)(ws + 0);                            // 67,108,864 B
  unsigned short* candi = (unsigned short*)(ws + 0);       //  5,242,880 B (alias PQ)
  _Float16* xf = (_Float16*)(ws + 16777216);               //  8,388,608 B (alias PQ)
  float* sq = (float*)(ws + 67108864);                     //    262,144 B
  int* nbr = (int*)(ws + 67371008);                        //  4,194,304 B
  int* counts = (int*)(ws + 71565312);                     //    262,144 B
  int* cursor = (int*)(ws + 71827456);                     //    262,144 B
  int* srow = (int*)(ws + 72089600);                       //  4,194,304 B
  int* scol = (int*)(ws + 76283904);                       //  4,194,304 B
  _Float16* w2f = (_Float16*)(ws + 80478208);              //     32,768 B
  double* sq64 = (double*)(ws + 80543744);                 //    524,288 B  (end 81,068,032)

  hipMemsetAsync(d_out, 0, (size_t)out_size * sizeof(float), stream);
  hipMemsetAsync(counts, 0, (size_t)N_NODES * sizeof(int), stream);
  prep_weights_k<<<1, 256, 0, stream>>>(W2, w2f);
  prep_node_k<<<N_NODES / 256, 256, 0, stream>>>(x, sq, sq64, xf);
  knn1_k<<<N_NODES / 128, 256, 0, stream>>>(xf, sq, candi);
  knn2_k<<<N_NODES / 256, 256, 0, stream>>>(x, sq64, candi, nbr, counts);
  scan_k<<<1, 256, 0, stream>>>(counts, cursor);
  scatter_k<<<NEDGE / 256, 256, 0, stream>>>(nbr, cursor, srow, scol);
  prep_pq_k<<<N_NODES / 16, 256, 0, stream>>>(x, W1, b1, PQ);
  gemm2_k<<<2048, 256, 0, stream>>>(PQ, srow, scol, w2f, b2, out);
  final_k<<<(N_NODES * HDIM) / 256, 256, 0, stream>>>(out, counts);
}

// Round 10
// 889.042 us; speedup vs baseline: 1.5299x; 1.0883x over previous
//
#include <hip/hip_runtime.h>

typedef __attribute__((ext_vector_type(4))) float f32x4;
typedef __attribute__((ext_vector_type(8))) short s16x8;
typedef __attribute__((ext_vector_type(8))) _Float16 f16x8;

#define N_NODES 65536
#define GNPG 1024
#define FDIM 64
#define HDIM 128
#define KNN 16
#define JT 64      // knn j-tile
#define DSTR 68    // knn dist LDS row stride (f32)
#define SCAND 20   // per-subset candidate list (2 subsets/center)
#define NEDGE (N_NODES * KNN)
#define NT (NEDGE / 64)

// Build MFMA B-fragment-ordered fp16 copy of W2 (128x128).
// Frag layout (16x16x32): lane l holds B[k = 8*(l>>4)+j + 32*ks][col = ct*16 + (l&15)], j=0..7.
__global__ void prep_weights_k(const float* __restrict__ W2, _Float16* __restrict__ w2f) {
  int tid = threadIdx.x;
  for (int idx = tid; idx < 8 * 4 * 64 * 8; idx += 256) {
    int j = idx & 7, l = (idx >> 3) & 63, ks = (idx >> 9) & 3, ct = idx >> 11;
    int k = 8 * (l >> 4) + j + 32 * ks, col = ct * 16 + (l & 15);
    w2f[idx] = (_Float16)W2[k * 128 + col];
  }
}

// Per-node precompute: f64 sq norm (+f32 copy) and fp16 copy of x (row-major = frag order).
__global__ void prep_node_k(const float* __restrict__ x, float* __restrict__ sq,
                            double* __restrict__ sq64, _Float16* __restrict__ xf) {
  int n = blockIdx.x * 256 + threadIdx.x;
  const f32x4* xp = (const f32x4*)(x + (size_t)n * FDIM);
  double s0 = 0, s1 = 0;
#pragma unroll
  for (int c8 = 0; c8 < 8; ++c8) {
    f32x4 a = xp[2 * c8], b = xp[2 * c8 + 1];
    f16x8 h;
#pragma unroll
    for (int e = 0; e < 4; ++e) {
      h[e] = (_Float16)a[e];
      h[4 + e] = (_Float16)b[e];
      s0 = fma((double)a[e], (double)a[e], s0);
      s1 = fma((double)b[e], (double)b[e], s1);
    }
    *(f16x8*)(xf + (size_t)n * FDIM + c8 * 8) = h;
  }
  double s = s0 + s1;
  sq64[n] = s;
  sq[n] = (float)s;
}

// fp32 GEMM1 -> fp16 store: PQ16[n][0:128] = x@(W1_top - W1_bot); [128:256] = x@W1_bot + b1.
__global__ __launch_bounds__(256) void prep_pq_k(const float* __restrict__ x,
                                                 const float* __restrict__ W1,
                                                 const float* __restrict__ b1,
                                                 _Float16* __restrict__ PQ16) {
  __shared__ float WcL[64 * 256];   // 64KB
  __shared__ float xL[16 * 64];     // 4KB
  int tid = threadIdx.x;
  for (int i = tid; i < 64 * 256; i += 256) {
    int k = i >> 8, c = i & 255;
    WcL[i] = (c < 128) ? (W1[k * 128 + c] - W1[(k + 64) * 128 + c])
                       : W1[(k + 64) * 128 + (c - 128)];
  }
  int nbase = blockIdx.x * 16;
  for (int i = tid; i < 16 * 64; i += 256) xL[i] = x[(size_t)nbase * 64 + i];
  __syncthreads();
  int nl = tid >> 4, c0 = tid & 15;
  float acc[16];
#pragma unroll
  for (int j = 0; j < 16; ++j) acc[j] = 0.f;
  for (int k = 0; k < 64; ++k) {
    float xk = xL[nl * 64 + k];
    const float* wr = WcL + k * 256 + c0;
#pragma unroll
    for (int j = 0; j < 16; ++j) acc[j] = fmaf(xk, wr[16 * j], acc[j]);
  }
#pragma unroll
  for (int j = 0; j < 16; ++j) {
    int c = c0 + 16 * j;
    float b = (c >= 128) ? b1[c - 128] : 0.f;
    PQ16[(size_t)(nbase + nl) * 256 + c] = (_Float16)(acc[j] + b);
  }
}

// KNN stage 1 (fp16 MFMA): block = 128 centers of one graph. Per 64-col tile: stage fp16
// B-frags in LDS, 16 MFMA/wave, distances -> padded LDS, 2 threads/center scan 32 cols
// each keeping a register top-20. knn2's f64 rescore is the correctness authority.
__global__ __launch_bounds__(256) void knn1_k(const _Float16* __restrict__ xf,
                                              const float* __restrict__ sq,
                                              unsigned short* __restrict__ candi) {
  __shared__ float sq_l[GNPG];
  __shared__ __attribute__((aligned(16))) _Float16 bfL[512 * 8];
  __shared__ __attribute__((aligned(16))) float distL[128 * DSTR];
  int tid = threadIdx.x, lane = tid & 63, wave = tid >> 6;
  int g = blockIdx.x >> 3;
  int rb = (blockIdx.x & 7) * 128;
  const _Float16* xfg = xf + (size_t)g * GNPG * FDIM;
  for (int i = tid; i < GNPG; i += 256) sq_l[i] = sq[g * GNPG + i];
  f16x8 af[2][2];
#pragma unroll
  for (int rt = 0; rt < 2; ++rt)
#pragma unroll
    for (int ks = 0; ks < 2; ++ks) {
      size_t off = (size_t)(rb + wave * 32 + rt * 16 + (lane & 15)) * FDIM + (lane >> 4) * 8 + 32 * ks;
      af[rt][ks] = *(const f16x8*)(xfg + off);
    }
  float dl[SCAND]; int il[SCAND];
#pragma unroll
  for (int q = 0; q < SCAND; ++q) { dl[q] = 3.0e38f; il[q] = 0; }
  int c = tid >> 1, sub = tid & 1;
  for (int jt = 0; jt < GNPG / JT; ++jt) {
#pragma unroll
    for (int s2 = tid; s2 < 512; s2 += 256) {
      int ct = s2 >> 7, ks = (s2 >> 6) & 1, l = s2 & 63;
      size_t goff = (size_t)(jt * JT + ct * 16 + (l & 15)) * FDIM + (l >> 4) * 8 + 32 * ks;
      *(f16x8*)(bfL + s2 * 8) = *(const f16x8*)(xfg + goff);
    }
    __syncthreads();
    f32x4 acc[2][4];
#pragma unroll
    for (int rt = 0; rt < 2; ++rt)
#pragma unroll
      for (int ct = 0; ct < 4; ++ct) acc[rt][ct] = (f32x4){0.f, 0.f, 0.f, 0.f};
#pragma unroll
    for (int ks = 0; ks < 2; ++ks)
#pragma unroll
      for (int ct = 0; ct < 4; ++ct) {
        f16x8 bfr = *(const f16x8*)(bfL + ((ct * 2 + ks) * 64 + lane) * 8);
#pragma unroll
        for (int rt = 0; rt < 2; ++rt)
          acc[rt][ct] = __builtin_amdgcn_mfma_f32_16x16x32_f16(af[rt][ks], bfr, acc[rt][ct], 0, 0, 0);
      }
#pragma unroll
    for (int rt = 0; rt < 2; ++rt)
#pragma unroll
      for (int ct = 0; ct < 4; ++ct) {
        int coltl = ct * 16 + (lane & 15);
        int jlg = jt * JT + coltl;
        float sqj = sq_l[jlg];
#pragma unroll
        for (int r = 0; r < 4; ++r) {
          int row = wave * 32 + rt * 16 + (lane >> 4) * 4 + r;
          float d = sq_l[rb + row] + sqj - 2.f * acc[rt][ct][r];
          if (rb + row == jlg) d = 3.0e38f;
          distL[row * DSTR + coltl] = d;
        }
      }
    __syncthreads();
#pragma unroll 2
    for (int i = 0; i < 8; ++i) {
      f32x4 v = *(const f32x4*)(distL + c * DSTR + sub * 32 + i * 4);
#pragma unroll
      for (int e = 0; e < 4; ++e) {
        float d = v[e];
        if (d < dl[SCAND - 1]) {
          dl[SCAND - 1] = d; il[SCAND - 1] = jt * JT + sub * 32 + i * 4 + e;
#pragma unroll
          for (int p = SCAND - 1; p >= 1; --p) {
            float a0 = dl[p - 1], a1 = dl[p];
            int b0 = il[p - 1], b1v = il[p];
            bool cc = a1 < a0;
            dl[p - 1] = cc ? a1 : a0; dl[p] = cc ? a0 : a1;
            il[p - 1] = cc ? b1v : b0; il[p] = cc ? b0 : b1v;
          }
        }
      }
    }
  }
  int nglob = g * GNPG + rb + c;
  unsigned short* ii = candi + (size_t)nglob * (2 * SCAND) + sub * SCAND;
#pragma unroll
  for (int q = 0; q < SCAND; ++q) ii[q] = (unsigned short)il[q];
}

// KNN stage 2: 1 thread/center, non-unrolled loop over all 40 candidates, exact f64
// distance, compile-time-unrolled insertion into a 16-deep (d64, idx)-sorted register list.
__global__ __launch_bounds__(256) void knn2_k(const float* __restrict__ x,
                                              const double* __restrict__ sq64,
                                              const unsigned short* __restrict__ candi,
                                              int* __restrict__ nbr, int* __restrict__ counts) {
  int n = blockIdx.x * 256 + threadIdx.x;
  int gbase = n & ~(GNPG - 1);
  f32x4 xi[16];
  const f32x4* xp = (const f32x4*)(x + (size_t)n * FDIM);
#pragma unroll
  for (int f = 0; f < 16; ++f) xi[f] = xp[f];
  double sq64i = sq64[n];
  double dl[KNN]; int il[KNN];
#pragma unroll
  for (int q = 0; q < KNN; ++q) { dl[q] = 1.0e300; il[q] = 0x7FFFFFFF; }
  const unsigned short* ii = candi + (size_t)n * (2 * SCAND);
#pragma unroll 1
  for (int t = 0; t < 2 * SCAND; ++t) {
    int jl = ii[t];
    int j = gbase + jl;
    const f32x4* xj = (const f32x4*)(x + (size_t)j * FDIM);
    double t0 = 0, t1 = 0, t2 = 0, t3 = 0;
#pragma unroll
    for (int f = 0; f < 16; ++f) {
      f32x4 a = xi[f], b = xj[f];
      t0 = fma((double)a[0], (double)b[0], t0);
      t1 = fma((double)a[1], (double)b[1], t1);
      t2 = fma((double)a[2], (double)b[2], t2);
      t3 = fma((double)a[3], (double)b[3], t3);
    }
    double d = sq64i + sq64[j] - 2.0 * ((t0 + t1) + (t2 + t3));
    bool ins = (d < dl[KNN - 1]) || (d == dl[KNN - 1] && jl < il[KNN - 1]);
    if (ins) {
      dl[KNN - 1] = d; il[KNN - 1] = jl;
#pragma unroll
      for (int p = KNN - 1; p >= 1; --p) {
        double a0 = dl[p - 1], a1 = dl[p];
        int b0 = il[p - 1], b1v = il[p];
        bool cc = (a1 < a0) || (a1 == a0 && b1v < b0);
        dl[p - 1] = cc ? a1 : a0; dl[p] = cc ? a0 : a1;
        il[p - 1] = cc ? b1v : b0; il[p] = cc ? b0 : b1v;
      }
    }
  }
#pragma unroll
  for (int q = 0; q < KNN; ++q) {
    int gidx = gbase + il[q];
    nbr[(size_t)n * KNN + q] = gidx;
    atomicAdd(&counts[gidx], 1);
  }
}

__global__ void scan_k(const int* __restrict__ counts, int* __restrict__ cursor) {
  __shared__ int part[256];
  int t = threadIdx.x, base = t * 256;
  int s = 0;
  for (int i = 0; i < 256; ++i) s += counts[base + i];
  part[t] = s;
  __syncthreads();
  if (t == 0) {
    int run = 0;
    for (int i = 0; i < 256; ++i) { int v = part[i]; part[i] = run; run += v; }
  }
  __syncthreads();
  int run = part[t];
  for (int i = 0; i < 256; ++i) { int idx = base + i; cursor[idx] = run; run += counts[idx]; }
}

__global__ void scatter_k(const int* __restrict__ nbr, int* __restrict__ cursor,
                          int* __restrict__ srow, int* __restrict__ scol) {
  int e = blockIdx.x * 256 + threadIdx.x;
  int r = nbr[e], c = e >> 4;
  int pos = atomicAdd(&cursor[r], 1);
  srow[pos] = r; scol[pos] = c;
}

// gemm2 v2: fp16 PQ gather with 2-deep register prefetch pipeline; 16KB LDS where the
// fp16 A tile and the fp16 h2 tile alias (barrier-separated); h2 swizzled (row&12)<<3;
// segmented sum by sorted row -> atomicAdd.
__global__ __launch_bounds__(256) void gemm2_k(const _Float16* __restrict__ PQ16,
                                               const int* __restrict__ srow, const int* __restrict__ scol,
                                               const _Float16* __restrict__ w2f,
                                               const float* __restrict__ b2,
                                               float* __restrict__ out) {
  __shared__ __attribute__((aligned(16))) char smem[16384];
  int tid = threadIdx.x, lane = tid & 63, wave = tid >> 6;
  int cg = wave & 1, eg = wave >> 1;
  f16x8 wf[4][4];
#pragma unroll
  for (int ct = 0; ct < 4; ++ct)
#pragma unroll
    for (int ks = 0; ks < 4; ++ks)
      wf[ct][ks] = *(const f16x8*)(w2f + ((((cg * 4 + ct) * 4 + ks) * 64 + lane) * 8));
  float b2r[4];
#pragma unroll
  for (int ct = 0; ct < 4; ++ct) b2r[ct] = b2[cg * 64 + ct * 16 + (lane & 15)];

  int e_in = tid >> 2, qq = tid & 3;
  // prologue: prefetch tile 0's gather into registers
  f16x8 pf[8];
  {
    int e = blockIdx.x * 64 + e_in;
    int row = srow[e], colc = scol[e];
    const f16x8* Pp = (const f16x8*)(PQ16 + (size_t)row * 256 + qq * 32);
    const f16x8* Qp = (const f16x8*)(PQ16 + (size_t)colc * 256 + 128 + qq * 32);
#pragma unroll
    for (int i = 0; i < 4; ++i) { pf[i] = Pp[i]; pf[4 + i] = Qp[i]; }
  }
  for (int tile = blockIdx.x; tile < NT; tile += gridDim.x) {
    int base = tile * 64;
    // stage A (fp16) from prefetched regs
#pragma unroll
    for (int i = 0; i < 4; ++i) {
      f16x8 hv;
#pragma unroll
      for (int e = 0; e < 8; ++e) {
        float sv = (float)pf[i][e] + (float)pf[4 + i][e];
        hv[e] = (_Float16)(sv > 0.f ? sv : 0.f);
      }
      int byteoff = e_in * 256 + ((2 * (qq * 32 + i * 8)) ^ ((e_in & 7) << 4));
      *(f16x8*)(smem + byteoff) = hv;
    }
    // issue next tile's gather (overlaps MFMA + h2 + reduce below)
    int ntile = tile + gridDim.x;
    if (ntile < NT) {
      int e = ntile * 64 + e_in;
      int row = srow[e], colc = scol[e];
      const f16x8* Pp = (const f16x8*)(PQ16 + (size_t)row * 256 + qq * 32);
      const f16x8* Qp = (const f16x8*)(PQ16 + (size_t)colc * 256 + 128 + qq * 32);
#pragma unroll
      for (int i = 0; i < 4; ++i) { pf[i] = Pp[i]; pf[4 + i] = Qp[i]; }
    }
    __syncthreads();   // A visible
    f32x4 acc[2][4];
#pragma unroll
    for (int rt = 0; rt < 2; ++rt)
#pragma unroll
      for (int ct = 0; ct < 4; ++ct) acc[rt][ct] = (f32x4){0.f, 0.f, 0.f, 0.f};
#pragma unroll
    for (int rt = 0; rt < 2; ++rt) {
      int rowL = eg * 32 + rt * 16 + (lane & 15);
#pragma unroll
      for (int ks = 0; ks < 4; ++ks) {
        int byteoff = rowL * 256 + ((16 * (lane >> 4) + 64 * ks) ^ ((rowL & 7) << 4));
        f16x8 a = *(const f16x8*)(smem + byteoff);
#pragma unroll
        for (int ct = 0; ct < 4; ++ct)
          acc[rt][ct] = __builtin_amdgcn_mfma_f32_16x16x32_f16(a, wf[ct][ks], acc[rt][ct], 0, 0, 0);
      }
    }
    __syncthreads();   // A consumed; smem becomes h2 (fp16 [64][128], (row&12)<<3 swizzle)
#pragma unroll
    for (int rt = 0; rt < 2; ++rt)
#pragma unroll
      for (int ct = 0; ct < 4; ++ct) {
        int col = cg * 64 + ct * 16 + (lane & 15);
#pragma unroll
        for (int r = 0; r < 4; ++r) {
          int row_in = eg * 32 + rt * 16 + (lane >> 4) * 4 + r;
          float v = acc[rt][ct][r] + b2r[ct];
          v = v > 0.f ? v : 0.f;
          int byteoff = row_in * 256 + ((2 * col) ^ ((row_in & 12) << 3));
          *(_Float16*)(smem + byteoff) = (_Float16)v;
        }
      }
    __syncthreads();   // h2 visible
    {
      int col = tid & 127, estart = (tid >> 7) * 32;
      float a = 0.f;
      int prev = srow[base + estart];
#pragma unroll 8
      for (int e2 = estart; e2 < estart + 32; ++e2) {
        int r2 = srow[base + e2];
        if (r2 != prev) { atomicAdd(out + (size_t)prev * 128 + col, a); a = 0.f; prev = r2; }
        int byteoff = e2 * 256 + ((2 * col) ^ ((e2 & 12) << 3));
        a += (float)*(const _Float16*)(smem + byteoff);
      }
      atomicAdd(out + (size_t)prev * 128 + col, a);
    }
    __syncthreads();   // h2 consumed before next stage write
  }
}

__global__ void final_k(float* __restrict__ out, const int* __restrict__ counts) {
  int idx = blockIdx.x * 256 + threadIdx.x;
  int n = idx >> 7;
  int c = counts[n];
  c = c > 0 ? c : 1;
  out[idx] = out[idx] / (float)c;
}

extern "C" void kernel_launch(void* const* d_in, const int* in_sizes, int n_in,
                              void* d_out, int out_size, void* d_ws, size_t ws_size,
                              hipStream_t stream) {
  const float* x = (const float*)d_in[0];
  const float* W1 = (const float*)d_in[2];
  const float* b1 = (const float*)d_in[3];
  const float* W2 = (const float*)d_in[4];
  const float* b2 = (const float*)d_in[5];
  float* out = (float*)d_out;
  char* ws = (char*)d_ws;

  // PQ16 region (32 MB) is aliased by KNN-phase buffers (candi/xf): all KNN kernels run
  // BEFORE prep_pq_k writes PQ16, so lifetimes are disjoint (stream-ordered).
  _Float16* PQ16 = (_Float16*)(ws + 0);                    // 33,554,432 B
  unsigned short* candi = (unsigned short*)(ws + 0);       //  5,242,880 B (alias PQ16)
  _Float16* xf = (_Float16*)(ws + 16777216);               //  8,388,608 B (alias PQ16)
  float* sq = (float*)(ws + 67108864);                     //    262,144 B
  int* nbr = (int*)(ws + 67371008);                        //  4,194,304 B
  int* counts = (int*)(ws + 71565312);                     //    262,144 B
  int* cursor = (int*)(ws + 71827456);                     //    262,144 B
  int* srow = (int*)(ws + 72089600);                       //  4,194,304 B
  int* scol = (int*)(ws + 76283904);                       //  4,194,304 B
  _Float16* w2f = (_Float16*)(ws + 80478208);              //     32,768 B
  double* sq64 = (double*)(ws + 80543744);                 //    524,288 B  (end 81,068,032)

  hipMemsetAsync(d_out, 0, (size_t)out_size * sizeof(float), stream);
  hipMemsetAsync(counts, 0, (size_t)N_NODES * sizeof(int), stream);
  prep_weights_k<<<1, 256, 0, stream>>>(W2, w2f);
  prep_node_k<<<N_NODES / 256, 256, 0, stream>>>(x, sq, sq64, xf);
  knn1_k<<<N_NODES / 128, 256, 0, stream>>>(xf, sq, candi);
  knn2_k<<<N_NODES / 256, 256, 0, stream>>>(x, sq64, candi, nbr, counts);
  scan_k<<<1, 256, 0, stream>>>(counts, cursor);
  scatter_k<<<NEDGE / 256, 256, 0, stream>>>(nbr, cursor, srow, scol);
  prep_pq_k<<<N_NODES / 16, 256, 0, stream>>>(x, W1, b1, PQ16);
  gemm2_k<<<2048, 256, 0, stream>>>(PQ16, srow, scol, w2f, b2, out);
  final_k<<<(N_NODES * HDIM) / 256, 256, 0, stream>>>(out, counts);
}

// Round 11
// 854.088 us; speedup vs baseline: 1.5925x; 1.0409x over previous
//
#include <hip/hip_runtime.h>

typedef __attribute__((ext_vector_type(4))) float f32x4;
typedef __attribute__((ext_vector_type(8))) short s16x8;
typedef __attribute__((ext_vector_type(8))) _Float16 f16x8;

#define N_NODES 65536
#define GNPG 1024
#define FDIM 64
#define HDIM 128
#define KNN 16
#define JT 64      // knn j-tile
#define DSTR 68    // knn dist LDS row stride (f32)
#define SCAND 20   // per-subset candidate list (2 subsets/center)
#define STKC 8     // per-lane survivor stack depth
#define NEDGE (N_NODES * KNN)
#define NT (NEDGE / 64)

// Build MFMA B-fragment-ordered fp16 copy of W2 (128x128).
// Frag layout (16x16x32): lane l holds B[k = 8*(l>>4)+j + 32*ks][col = ct*16 + (l&15)], j=0..7.
__global__ void prep_weights_k(const float* __restrict__ W2, _Float16* __restrict__ w2f) {
  int tid = threadIdx.x;
  for (int idx = tid; idx < 8 * 4 * 64 * 8; idx += 256) {
    int j = idx & 7, l = (idx >> 3) & 63, ks = (idx >> 9) & 3, ct = idx >> 11;
    int k = 8 * (l >> 4) + j + 32 * ks, col = ct * 16 + (l & 15);
    w2f[idx] = (_Float16)W2[k * 128 + col];
  }
}

// Per-node precompute: f64 sq norm (+f32 copy) and fp16 copy of x (row-major = frag order).
__global__ void prep_node_k(const float* __restrict__ x, float* __restrict__ sq,
                            double* __restrict__ sq64, _Float16* __restrict__ xf) {
  int n = blockIdx.x * 256 + threadIdx.x;
  const f32x4* xp = (const f32x4*)(x + (size_t)n * FDIM);
  double s0 = 0, s1 = 0;
#pragma unroll
  for (int c8 = 0; c8 < 8; ++c8) {
    f32x4 a = xp[2 * c8], b = xp[2 * c8 + 1];
    f16x8 h;
#pragma unroll
    for (int e = 0; e < 4; ++e) {
      h[e] = (_Float16)a[e];
      h[4 + e] = (_Float16)b[e];
      s0 = fma((double)a[e], (double)a[e], s0);
      s1 = fma((double)b[e], (double)b[e], s1);
    }
    *(f16x8*)(xf + (size_t)n * FDIM + c8 * 8) = h;
  }
  double s = s0 + s1;
  sq64[n] = s;
  sq[n] = (float)s;
}

// fp32 GEMM1 -> fp16 store: PQ16[n][0:128] = x@(W1_top - W1_bot); [128:256] = x@W1_bot + b1.
__global__ __launch_bounds__(256) void prep_pq_k(const float* __restrict__ x,
                                                 const float* __restrict__ W1,
                                                 const float* __restrict__ b1,
                                                 _Float16* __restrict__ PQ16) {
  __shared__ float WcL[64 * 256];   // 64KB
  __shared__ float xL[16 * 64];     // 4KB
  int tid = threadIdx.x;
  for (int i = tid; i < 64 * 256; i += 256) {
    int k = i >> 8, c = i & 255;
    WcL[i] = (c < 128) ? (W1[k * 128 + c] - W1[(k + 64) * 128 + c])
                       : W1[(k + 64) * 128 + (c - 128)];
  }
  int nbase = blockIdx.x * 16;
  for (int i = tid; i < 16 * 64; i += 256) xL[i] = x[(size_t)nbase * 64 + i];
  __syncthreads();
  int nl = tid >> 4, c0 = tid & 15;
  float acc[16];
#pragma unroll
  for (int j = 0; j < 16; ++j) acc[j] = 0.f;
  for (int k = 0; k < 64; ++k) {
    float xk = xL[nl * 64 + k];
    const float* wr = WcL + k * 256 + c0;
#pragma unroll
    for (int j = 0; j < 16; ++j) acc[j] = fmaf(xk, wr[16 * j], acc[j]);
  }
#pragma unroll
  for (int j = 0; j < 16; ++j) {
    int c = c0 + 16 * j;
    float b = (c >= 128) ? b1[c - 128] : 0.f;
    PQ16[(size_t)(nbase + nl) * 256 + c] = (_Float16)(acc[j] + b);
  }
}

// KNN stage 1 (fp16 MFMA): block = 128 centers of one graph. Per 64-col tile: stage fp16
// B-frags in LDS, MFMA distances -> padded LDS. Scan: branch-free filter (pack d,idx ->
// per-lane LDS stack, sp += d<kick) + wave-joint drains that run the insertion ladder
// only on survivors. knn2's f64 rescore is the correctness authority.
__global__ __launch_bounds__(256) void knn1_k(const _Float16* __restrict__ xf,
                                              const float* __restrict__ sq,
                                              unsigned short* __restrict__ candi) {
  __shared__ float sq_l[GNPG];
  __shared__ __attribute__((aligned(16))) _Float16 bfL[512 * 8];
  __shared__ __attribute__((aligned(16))) float distL[128 * DSTR];
  __shared__ __attribute__((aligned(16))) uint2 stk[STKC * 256];   // [sp][tid] layout
  int tid = threadIdx.x, lane = tid & 63, wave = tid >> 6;
  int g = blockIdx.x >> 3;
  int rb = (blockIdx.x & 7) * 128;
  const _Float16* xfg = xf + (size_t)g * GNPG * FDIM;
  for (int i = tid; i < GNPG; i += 256) sq_l[i] = sq[g * GNPG + i];
  f16x8 af[2][2];
#pragma unroll
  for (int rt = 0; rt < 2; ++rt)
#pragma unroll
    for (int ks = 0; ks < 2; ++ks) {
      size_t off = (size_t)(rb + wave * 32 + rt * 16 + (lane & 15)) * FDIM + (lane >> 4) * 8 + 32 * ks;
      af[rt][ks] = *(const f16x8*)(xfg + off);
    }
  float dl[SCAND]; int il[SCAND];
#pragma unroll
  for (int q = 0; q < SCAND; ++q) { dl[q] = 3.0e38f; il[q] = 0; }
  int c = tid >> 1, sub = tid & 1;
  int sp = 0;
  for (int jt = 0; jt < GNPG / JT; ++jt) {
#pragma unroll
    for (int s2 = tid; s2 < 512; s2 += 256) {
      int ct = s2 >> 7, ks = (s2 >> 6) & 1, l = s2 & 63;
      size_t goff = (size_t)(jt * JT + ct * 16 + (l & 15)) * FDIM + (l >> 4) * 8 + 32 * ks;
      *(f16x8*)(bfL + s2 * 8) = *(const f16x8*)(xfg + goff);
    }
    __syncthreads();
    f32x4 acc[2][4];
#pragma unroll
    for (int rt = 0; rt < 2; ++rt)
#pragma unroll
      for (int ct = 0; ct < 4; ++ct) acc[rt][ct] = (f32x4){0.f, 0.f, 0.f, 0.f};
#pragma unroll
    for (int ks = 0; ks < 2; ++ks)
#pragma unroll
      for (int ct = 0; ct < 4; ++ct) {
        f16x8 bfr = *(const f16x8*)(bfL + ((ct * 2 + ks) * 64 + lane) * 8);
#pragma unroll
        for (int rt = 0; rt < 2; ++rt)
          acc[rt][ct] = __builtin_amdgcn_mfma_f32_16x16x32_f16(af[rt][ks], bfr, acc[rt][ct], 0, 0, 0);
      }
#pragma unroll
    for (int rt = 0; rt < 2; ++rt)
#pragma unroll
      for (int ct = 0; ct < 4; ++ct) {
        int coltl = ct * 16 + (lane & 15);
        int jlg = jt * JT + coltl;
        float sqj = sq_l[jlg];
#pragma unroll
        for (int r = 0; r < 4; ++r) {
          int row = wave * 32 + rt * 16 + (lane >> 4) * 4 + r;
          float d = sq_l[rb + row] + sqj - 2.f * acc[rt][ct][r];
          if (rb + row == jlg) d = 3.0e38f;
          distL[row * DSTR + coltl] = d;
        }
      }
    __syncthreads();
    // scan 32 candidates (branch-free filter into stack; joint drains)
    int cbase = jt * JT + sub * 32;
    const float* dp = distL + c * DSTR + sub * 32;
#pragma unroll 2
    for (int i = 0; i < 8; ++i) {
      // joint drain when any lane is within 4 of full (sp can grow by <=4 below)
      if (__any(sp > STKC - 4)) {
        while (__any(sp > 0)) {
          if (sp > 0) {
            --sp;
            uint2 pk = stk[sp * 256 + tid];
            float dd = __uint_as_float(pk.x);
            if (dd < dl[SCAND - 1]) {
              int ji = (int)pk.y;
              dl[SCAND - 1] = dd; il[SCAND - 1] = ji;
#pragma unroll
              for (int p = SCAND - 1; p >= 1; --p) {
                float a0 = dl[p - 1], a1 = dl[p];
                int b0 = il[p - 1], b1v = il[p];
                bool cc = a1 < a0;
                dl[p - 1] = cc ? a1 : a0; dl[p] = cc ? a0 : a1;
                il[p - 1] = cc ? b1v : b0; il[p] = cc ? b0 : b1v;
              }
            }
          }
        }
      }
      f32x4 v = *(const f32x4*)(dp + i * 4);
#pragma unroll
      for (int e = 0; e < 4; ++e) {
        float d = v[e];
        uint2 pk;
        pk.x = __float_as_uint(d);
        pk.y = (unsigned)(cbase + i * 4 + e);
        stk[sp * 256 + tid] = pk;                 // unconditional store
        sp += (d < dl[SCAND - 1]) ? 1 : 0;        // keep only if it beats kick
      }
    }
  }
  // final drain
  while (__any(sp > 0)) {
    if (sp > 0) {
      --sp;
      uint2 pk = stk[sp * 256 + tid];
      float dd = __uint_as_float(pk.x);
      if (dd < dl[SCAND - 1]) {
        int ji = (int)pk.y;
        dl[SCAND - 1] = dd; il[SCAND - 1] = ji;
#pragma unroll
        for (int p = SCAND - 1; p >= 1; --p) {
          float a0 = dl[p - 1], a1 = dl[p];
          int b0 = il[p - 1], b1v = il[p];
          bool cc = a1 < a0;
          dl[p - 1] = cc ? a1 : a0; dl[p] = cc ? a0 : a1;
          il[p - 1] = cc ? b1v : b0; il[p] = cc ? b0 : b1v;
        }
      }
    }
  }
  int nglob = g * GNPG + rb + c;
  unsigned short* ii = candi + (size_t)nglob * (2 * SCAND) + sub * SCAND;
#pragma unroll
  for (int q = 0; q < SCAND; ++q) ii[q] = (unsigned short)il[q];
}

// KNN stage 2: 1 thread/center, non-unrolled loop over all 40 candidates, exact f64
// distance, compile-time-unrolled insertion into a 16-deep (d64, idx)-sorted register list.
__global__ __launch_bounds__(256) void knn2_k(const float* __restrict__ x,
                                              const double* __restrict__ sq64,
                                              const unsigned short* __restrict__ candi,
                                              int* __restrict__ nbr, int* __restrict__ counts) {
  int n = blockIdx.x * 256 + threadIdx.x;
  int gbase = n & ~(GNPG - 1);
  f32x4 xi[16];
  const f32x4* xp = (const f32x4*)(x + (size_t)n * FDIM);
#pragma unroll
  for (int f = 0; f < 16; ++f) xi[f] = xp[f];
  double sq64i = sq64[n];
  double dl[KNN]; int il[KNN];
#pragma unroll
  for (int q = 0; q < KNN; ++q) { dl[q] = 1.0e300; il[q] = 0x7FFFFFFF; }
  const unsigned short* ii = candi + (size_t)n * (2 * SCAND);
#pragma unroll 1
  for (int t = 0; t < 2 * SCAND; ++t) {
    int jl = ii[t];
    int j = gbase + jl;
    const f32x4* xj = (const f32x4*)(x + (size_t)j * FDIM);
    double t0 = 0, t1 = 0, t2 = 0, t3 = 0;
#pragma unroll
    for (int f = 0; f < 16; ++f) {
      f32x4 a = xi[f], b = xj[f];
      t0 = fma((double)a[0], (double)b[0], t0);
      t1 = fma((double)a[1], (double)b[1], t1);
      t2 = fma((double)a[2], (double)b[2], t2);
      t3 = fma((double)a[3], (double)b[3], t3);
    }
    double d = sq64i + sq64[j] - 2.0 * ((t0 + t1) + (t2 + t3));
    bool ins = (d < dl[KNN - 1]) || (d == dl[KNN - 1] && jl < il[KNN - 1]);
    if (ins) {
      dl[KNN - 1] = d; il[KNN - 1] = jl;
#pragma unroll
      for (int p = KNN - 1; p >= 1; --p) {
        double a0 = dl[p - 1], a1 = dl[p];
        int b0 = il[p - 1], b1v = il[p];
        bool cc = (a1 < a0) || (a1 == a0 && b1v < b0);
        dl[p - 1] = cc ? a1 : a0; dl[p] = cc ? a0 : a1;
        il[p - 1] = cc ? b1v : b0; il[p] = cc ? b0 : b1v;
      }
    }
  }
#pragma unroll
  for (int q = 0; q < KNN; ++q) {
    int gidx = gbase + il[q];
    nbr[(size_t)n * KNN + q] = gidx;
    atomicAdd(&counts[gidx], 1);
  }
}

__global__ void scan_k(const int* __restrict__ counts, int* __restrict__ cursor) {
  __shared__ int part[256];
  int t = threadIdx.x, base = t * 256;
  int s = 0;
  for (int i = 0; i < 256; ++i) s += counts[base + i];
  part[t] = s;
  __syncthreads();
  if (t == 0) {
    int run = 0;
    for (int i = 0; i < 256; ++i) { int v = part[i]; part[i] = run; run += v; }
  }
  __syncthreads();
  int run = part[t];
  for (int i = 0; i < 256; ++i) { int idx = base + i; cursor[idx] = run; run += counts[idx]; }
}

__global__ void scatter_k(const int* __restrict__ nbr, int* __restrict__ cursor,
                          int* __restrict__ srow, int* __restrict__ scol) {
  int e = blockIdx.x * 256 + threadIdx.x;
  int r = nbr[e], c = e >> 4;
  int pos = atomicAdd(&cursor[r], 1);
  srow[pos] = r; scol[pos] = c;
}

// gemm2: fp16 PQ gather with 2-deep register prefetch pipeline; 16KB LDS where the
// fp16 A tile and the fp16 h2 tile alias (barrier-separated); h2 swizzled (row&12)<<3;
// segmented sum by sorted row -> atomicAdd.
__global__ __launch_bounds__(256) void gemm2_k(const _Float16* __restrict__ PQ16,
                                               const int* __restrict__ srow, const int* __restrict__ scol,
                                               const _Float16* __restrict__ w2f,
                                               const float* __restrict__ b2,
                                               float* __restrict__ out) {
  __shared__ __attribute__((aligned(16))) char smem[16384];
  int tid = threadIdx.x, lane = tid & 63, wave = tid >> 6;
  int cg = wave & 1, eg = wave >> 1;
  f16x8 wf[4][4];
#pragma unroll
  for (int ct = 0; ct < 4; ++ct)
#pragma unroll
    for (int ks = 0; ks < 4; ++ks)
      wf[ct][ks] = *(const f16x8*)(w2f + ((((cg * 4 + ct) * 4 + ks) * 64 + lane) * 8));
  float b2r[4];
#pragma unroll
  for (int ct = 0; ct < 4; ++ct) b2r[ct] = b2[cg * 64 + ct * 16 + (lane & 15)];

  int e_in = tid >> 2, qq = tid & 3;
  f16x8 pf[8];
  {
    int e = blockIdx.x * 64 + e_in;
    int row = srow[e], colc = scol[e];
    const f16x8* Pp = (const f16x8*)(PQ16 + (size_t)row * 256 + qq * 32);
    const f16x8* Qp = (const f16x8*)(PQ16 + (size_t)colc * 256 + 128 + qq * 32);
#pragma unroll
    for (int i = 0; i < 4; ++i) { pf[i] = Pp[i]; pf[4 + i] = Qp[i]; }
  }
  for (int tile = blockIdx.x; tile < NT; tile += gridDim.x) {
    int base = tile * 64;
#pragma unroll
    for (int i = 0; i < 4; ++i) {
      f16x8 hv;
#pragma unroll
      for (int e = 0; e < 8; ++e) {
        float sv = (float)pf[i][e] + (float)pf[4 + i][e];
        hv[e] = (_Float16)(sv > 0.f ? sv : 0.f);
      }
      int byteoff = e_in * 256 + ((2 * (qq * 32 + i * 8)) ^ ((e_in & 7) << 4));
      *(f16x8*)(smem + byteoff) = hv;
    }
    int ntile = tile + gridDim.x;
    if (ntile < NT) {
      int e = ntile * 64 + e_in;
      int row = srow[e], colc = scol[e];
      const f16x8* Pp = (const f16x8*)(PQ16 + (size_t)row * 256 + qq * 32);
      const f16x8* Qp = (const f16x8*)(PQ16 + (size_t)colc * 256 + 128 + qq * 32);
#pragma unroll
      for (int i = 0; i < 4; ++i) { pf[i] = Pp[i]; pf[4 + i] = Qp[i]; }
    }
    __syncthreads();
    f32x4 acc[2][4];
#pragma unroll
    for (int rt = 0; rt < 2; ++rt)
#pragma unroll
      for (int ct = 0; ct < 4; ++ct) acc[rt][ct] = (f32x4){0.f, 0.f, 0.f, 0.f};
#pragma unroll
    for (int rt = 0; rt < 2; ++rt) {
      int rowL = eg * 32 + rt * 16 + (lane & 15);
#pragma unroll
      for (int ks = 0; ks < 4; ++ks) {
        int byteoff = rowL * 256 + ((16 * (lane >> 4) + 64 * ks) ^ ((rowL & 7) << 4));
        f16x8 a = *(const f16x8*)(smem + byteoff);
#pragma unroll
        for (int ct = 0; ct < 4; ++ct)
          acc[rt][ct] = __builtin_amdgcn_mfma_f32_16x16x32_f16(a, wf[ct][ks], acc[rt][ct], 0, 0, 0);
      }
    }
    __syncthreads();
#pragma unroll
    for (int rt = 0; rt < 2; ++rt)
#pragma unroll
      for (int ct = 0; ct < 4; ++ct) {
        int col = cg * 64 + ct * 16 + (lane & 15);
#pragma unroll
        for (int r = 0; r < 4; ++r) {
          int row_in = eg * 32 + rt * 16 + (lane >> 4) * 4 + r;
          float v = acc[rt][ct][r] + b2r[ct];
          v = v > 0.f ? v : 0.f;
          int byteoff = row_in * 256 + ((2 * col) ^ ((row_in & 12) << 3));
          *(_Float16*)(smem + byteoff) = (_Float16)v;
        }
      }
    __syncthreads();
    {
      int col = tid & 127, estart = (tid >> 7) * 32;
      float a = 0.f;
      int prev = srow[base + estart];
#pragma unroll 8
      for (int e2 = estart; e2 < estart + 32; ++e2) {
        int r2 = srow[base + e2];
        if (r2 != prev) { atomicAdd(out + (size_t)prev * 128 + col, a); a = 0.f; prev = r2; }
        int byteoff = e2 * 256 + ((2 * col) ^ ((e2 & 12) << 3));
        a += (float)*(const _Float16*)(smem + byteoff);
      }
      atomicAdd(out + (size_t)prev * 128 + col, a);
    }
    __syncthreads();
  }
}

__global__ void final_k(float* __restrict__ out, const int* __restrict__ counts) {
  int idx = blockIdx.x * 256 + threadIdx.x;
  int n = idx >> 7;
  int c = counts[n];
  c = c > 0 ? c : 1;
  out[idx] = out[idx] / (float)c;
}

extern "C" void kernel_launch(void* const* d_in, const int* in_sizes, int n_in,
                              void* d_out, int out_size, void* d_ws, size_t ws_size,
                              hipStream_t stream) {
  const float* x = (const float*)d_in[0];
  const float* W1 = (const float*)d_in[2];
  const float* b1 = (const float*)d_in[3];
  const float* W2 = (const float*)d_in[4];
  const float* b2 = (const float*)d_in[5];
  float* out = (float*)d_out;
  char* ws = (char*)d_ws;

  // PQ16 region (32 MB) is aliased by KNN-phase buffers (candi/xf): all KNN kernels run
  // BEFORE prep_pq_k writes PQ16, so lifetimes are disjoint (stream-ordered).
  _Float16* PQ16 = (_Float16*)(ws + 0);                    // 33,554,432 B
  unsigned short* candi = (unsigned short*)(ws + 0);       //  5,242,880 B (alias PQ16)
  _Float16* xf = (_Float16*)(ws + 16777216);               //  8,388,608 B (alias PQ16)
  float* sq = (float*)(ws + 67108864);                     //    262,144 B
  int* nbr = (int*)(ws + 67371008);                        //  4,194,304 B
  int* counts = (int*)(ws + 71565312);                     //    262,144 B
  int* cursor = (int*)(ws + 71827456);                     //    262,144 B
  int* srow = (int*)(ws + 72089600);                       //  4,194,304 B
  int* scol = (int*)(ws + 76283904);                       //  4,194,304 B
  _Float16* w2f = (_Float16*)(ws + 80478208);              //     32,768 B
  double* sq64 = (double*)(ws + 80543744);                 //    524,288 B  (end 81,068,032)

  hipMemsetAsync(d_out, 0, (size_t)out_size * sizeof(float), stream);
  hipMemsetAsync(counts, 0, (size_t)N_NODES * sizeof(int), stream);
  prep_weights_k<<<1, 256, 0, stream>>>(W2, w2f);
  prep_node_k<<<N_NODES / 256, 256, 0, stream>>>(x, sq, sq64, xf);
  knn1_k<<<N_NODES / 128, 256, 0, stream>>>(xf, sq, candi);
  knn2_k<<<N_NODES / 256, 256, 0, stream>>>(x, sq64, candi, nbr, counts);
  scan_k<<<1, 256, 0, stream>>>(counts, cursor);
  scatter_k<<<NEDGE / 256, 256, 0, stream>>>(nbr, cursor, srow, scol);
  prep_pq_k<<<N_NODES / 16, 256, 0, stream>>>(x, W1, b1, PQ16);
  gemm2_k<<<2048, 256, 0, stream>>>(PQ16, srow, scol, w2f, b2, out);
  final_k<<<(N_NODES * HDIM) / 256, 256, 0, stream>>>(out, counts);
}

// Round 12
// 760.572 us; speedup vs baseline: 1.7884x; 1.1230x over previous
//
#include <hip/hip_runtime.h>

typedef __attribute__((ext_vector_type(4))) float f32x4;
typedef __attribute__((ext_vector_type(4))) unsigned int u32x4;
typedef __attribute__((ext_vector_type(8))) short s16x8;
typedef __attribute__((ext_vector_type(8))) _Float16 f16x8;

#define N_NODES 65536
#define GNPG 1024
#define FDIM 64
#define HDIM 128
#define KNN 16
#define JT 64      // knn j-tile
#define DSTR 68    // knn key LDS row stride (u32), padded vs 64 to break bank conflicts
#define SCAND 20   // per-subset candidate list (2 subsets/center)
#define STKC 6     // per-lane survivor stack depth (u32 keys)
#define NEDGE (N_NODES * KNN)
#define NT (NEDGE / 64)

// Build MFMA B-fragment-ordered fp16 copy of W2 (128x128).
// Frag layout (16x16x32): lane l holds B[k = 8*(l>>4)+j + 32*ks][col = ct*16 + (l&15)], j=0..7.
__global__ void prep_weights_k(const float* __restrict__ W2, _Float16* __restrict__ w2f) {
  int tid = threadIdx.x;
  for (int idx = tid; idx < 8 * 4 * 64 * 8; idx += 256) {
    int j = idx & 7, l = (idx >> 3) & 63, ks = (idx >> 9) & 3, ct = idx >> 11;
    int k = 8 * (l >> 4) + j + 32 * ks, col = ct * 16 + (l & 15);
    w2f[idx] = (_Float16)W2[k * 128 + col];
  }
}

// Per-node precompute: f64 sq norm (+f32 copy) and fp16 copy of x (row-major = frag order).
__global__ void prep_node_k(const float* __restrict__ x, float* __restrict__ sq,
                            double* __restrict__ sq64, _Float16* __restrict__ xf) {
  int n = blockIdx.x * 256 + threadIdx.x;
  const f32x4* xp = (const f32x4*)(x + (size_t)n * FDIM);
  double s0 = 0, s1 = 0;
#pragma unroll
  for (int c8 = 0; c8 < 8; ++c8) {
    f32x4 a = xp[2 * c8], b = xp[2 * c8 + 1];
    f16x8 h;
#pragma unroll
    for (int e = 0; e < 4; ++e) {
      h[e] = (_Float16)a[e];
      h[4 + e] = (_Float16)b[e];
      s0 = fma((double)a[e], (double)a[e], s0);
      s1 = fma((double)b[e], (double)b[e], s1);
    }
    *(f16x8*)(xf + (size_t)n * FDIM + c8 * 8) = h;
  }
  double s = s0 + s1;
  sq64[n] = s;
  sq[n] = (float)s;
}

// fp32 GEMM1 -> fp16 store: PQ16[n][0:128] = x@(W1_top - W1_bot); [128:256] = x@W1_bot + b1.
__global__ __launch_bounds__(256) void prep_pq_k(const float* __restrict__ x,
                                                 const float* __restrict__ W1,
                                                 const float* __restrict__ b1,
                                                 _Float16* __restrict__ PQ16) {
  __shared__ float WcL[64 * 256];   // 64KB
  __shared__ float xL[16 * 64];     // 4KB
  int tid = threadIdx.x;
  for (int i = tid; i < 64 * 256; i += 256) {
    int k = i >> 8, c = i & 255;
    WcL[i] = (c < 128) ? (W1[k * 128 + c] - W1[(k + 64) * 128 + c])
                       : W1[(k + 64) * 128 + (c - 128)];
  }
  int nbase = blockIdx.x * 16;
  for (int i = tid; i < 16 * 64; i += 256) xL[i] = x[(size_t)nbase * 64 + i];
  __syncthreads();
  int nl = tid >> 4, c0 = tid & 15;
  float acc[16];
#pragma unroll
  for (int j = 0; j < 16; ++j) acc[j] = 0.f;
  for (int k = 0; k < 64; ++k) {
    float xk = xL[nl * 64 + k];
    const float* wr = WcL + k * 256 + c0;
#pragma unroll
    for (int j = 0; j < 16; ++j) acc[j] = fmaf(xk, wr[16 * j], acc[j]);
  }
#pragma unroll
  for (int j = 0; j < 16; ++j) {
    int c = c0 + 16 * j;
    float b = (c >= 128) ? b1[c - 128] : 0.f;
    PQ16[(size_t)(nbase + nl) * 256 + c] = (_Float16)(acc[j] + b);
  }
}

// KNN stage 1 (fp16 MFMA): block = 128 centers of one graph. Per 64-col tile: stage fp16
// B-frags in LDS, MFMA distances -> PACKED sortable u32 keys (monotonic-float-bits top 22 |
// local idx 10 bits) in padded LDS. Scan: branch-free filter into a per-lane u32 stack +
// wave-joint drains with a 2-op/stage u32 min/max ladder. knn2's f64 rescore is authority.
__global__ __launch_bounds__(256) void knn1_k(const _Float16* __restrict__ xf,
                                              const float* __restrict__ sq,
                                              unsigned short* __restrict__ candi) {
  __shared__ float sq_l[GNPG];                                       //  4KB
  __shared__ __attribute__((aligned(16))) _Float16 bfL[512 * 8];     //  8KB
  __shared__ __attribute__((aligned(16))) unsigned keyL[128 * DSTR]; // 34KB
  __shared__ __attribute__((aligned(16))) unsigned stk[STKC * 256];  //  6KB  (total 52KB -> 3/CU)
  int tid = threadIdx.x, lane = tid & 63, wave = tid >> 6;
  int g = blockIdx.x >> 3;
  int rb = (blockIdx.x & 7) * 128;
  const _Float16* xfg = xf + (size_t)g * GNPG * FDIM;
  for (int i = tid; i < GNPG; i += 256) sq_l[i] = sq[g * GNPG + i];
  f16x8 af[2][2];
#pragma unroll
  for (int rt = 0; rt < 2; ++rt)
#pragma unroll
    for (int ks = 0; ks < 2; ++ks) {
      size_t off = (size_t)(rb + wave * 32 + rt * 16 + (lane & 15)) * FDIM + (lane >> 4) * 8 + 32 * ks;
      af[rt][ks] = *(const f16x8*)(xfg + off);
    }
  unsigned dl[SCAND];
#pragma unroll
  for (int q = 0; q < SCAND; ++q) dl[q] = 0xFFFFFFFFu;
  int c = tid >> 1, sub = tid & 1;
  int sp = 0;
  for (int jt = 0; jt < GNPG / JT; ++jt) {
#pragma unroll
    for (int s2 = tid; s2 < 512; s2 += 256) {
      int ct = s2 >> 7, ks = (s2 >> 6) & 1, l = s2 & 63;
      size_t goff = (size_t)(jt * JT + ct * 16 + (l & 15)) * FDIM + (l >> 4) * 8 + 32 * ks;
      *(f16x8*)(bfL + s2 * 8) = *(const f16x8*)(xfg + goff);
    }
    __syncthreads();
    f32x4 acc[2][4];
#pragma unroll
    for (int rt = 0; rt < 2; ++rt)
#pragma unroll
      for (int ct = 0; ct < 4; ++ct) acc[rt][ct] = (f32x4){0.f, 0.f, 0.f, 0.f};
#pragma unroll
    for (int ks = 0; ks < 2; ++ks)
#pragma unroll
      for (int ct = 0; ct < 4; ++ct) {
        f16x8 bfr = *(const f16x8*)(bfL + ((ct * 2 + ks) * 64 + lane) * 8);
#pragma unroll
        for (int rt = 0; rt < 2; ++rt)
          acc[rt][ct] = __builtin_amdgcn_mfma_f32_16x16x32_f16(af[rt][ks], bfr, acc[rt][ct], 0, 0, 0);
      }
#pragma unroll
    for (int rt = 0; rt < 2; ++rt)
#pragma unroll
      for (int ct = 0; ct < 4; ++ct) {
        int coltl = ct * 16 + (lane & 15);
        int jlg = jt * JT + coltl;
        float sqj = sq_l[jlg];
#pragma unroll
        for (int r = 0; r < 4; ++r) {
          int row = wave * 32 + rt * 16 + (lane >> 4) * 4 + r;
          float d = sq_l[rb + row] + sqj - 2.f * acc[rt][ct][r];
          unsigned b = __float_as_uint(d);
          b ^= (unsigned)(((int)b >> 31) | 0x80000000);
          unsigned key = (b & 0xFFFFFC00u) | (unsigned)coltl;  // low 10 bits replaced below
          key = (b & 0xFFFFFC00u) | (unsigned)jlg;
          if (rb + row == jlg) key = 0xFFFFFFFFu;
          keyL[row * DSTR + coltl] = key;
        }
      }
    __syncthreads();
    const unsigned* kp = keyL + c * DSTR + sub * 32;
#pragma unroll 2
    for (int i = 0; i < 8; ++i) {
      if (__any(sp > STKC - 4)) {
        while (__any(sp > 0)) {
          if (sp > 0) {
            --sp;
            unsigned k = stk[sp * 256 + tid];
            if (k < dl[SCAND - 1]) {
              dl[SCAND - 1] = k;
#pragma unroll
              for (int p = SCAND - 1; p >= 1; --p) {
                unsigned mn = min(dl[p - 1], dl[p]);
                unsigned mx = max(dl[p - 1], dl[p]);
                dl[p - 1] = mn; dl[p] = mx;
              }
            }
          }
        }
      }
      u32x4 v = *(const u32x4*)(kp + i * 4);
#pragma unroll
      for (int e = 0; e < 4; ++e) {
        stk[sp * 256 + tid] = v[e];
        sp += (v[e] < dl[SCAND - 1]) ? 1 : 0;
      }
    }
  }
  while (__any(sp > 0)) {
    if (sp > 0) {
      --sp;
      unsigned k = stk[sp * 256 + tid];
      if (k < dl[SCAND - 1]) {
        dl[SCAND - 1] = k;
#pragma unroll
        for (int p = SCAND - 1; p >= 1; --p) {
          unsigned mn = min(dl[p - 1], dl[p]);
          unsigned mx = max(dl[p - 1], dl[p]);
          dl[p - 1] = mn; dl[p] = mx;
        }
      }
    }
  }
  int nglob = g * GNPG + rb + c;
  unsigned short* ii = candi + (size_t)nglob * (2 * SCAND) + sub * SCAND;
#pragma unroll
  for (int q = 0; q < SCAND; ++q) ii[q] = (unsigned short)(dl[q] & 1023u);
}

// KNN stage 2: 2 threads/center (512 blocks -> 2 blocks/CU). Each thread rescores its own
// sub's 20 candidates in exact f64 (non-unrolled loop, immediate-consume loads), keeps a
// 16-deep (d64, idx)-sorted register list; sorted lists merged 2-pointer via LDS by sub 0.
__global__ __launch_bounds__(256) void knn2_k(const float* __restrict__ x,
                                              const double* __restrict__ sq64,
                                              const unsigned short* __restrict__ candi,
                                              int* __restrict__ nbr, int* __restrict__ counts) {
  __shared__ double md[2][128][17];
  __shared__ unsigned short mi[2][128][17];
  int tid = threadIdx.x, c_local = tid >> 1, sub = tid & 1;
  int n = blockIdx.x * 128 + c_local;
  int gbase = n & ~(GNPG - 1);
  f32x4 xi[16];
  const f32x4* xp = (const f32x4*)(x + (size_t)n * FDIM);
#pragma unroll
  for (int f = 0; f < 16; ++f) xi[f] = xp[f];
  double sq64i = sq64[n];
  double dl[KNN]; int il[KNN];
#pragma unroll
  for (int q = 0; q < KNN; ++q) { dl[q] = 1.0e300; il[q] = 0x7FFFFFFF; }
  const unsigned short* ii = candi + (size_t)n * (2 * SCAND) + sub * SCAND;
#pragma unroll 1
  for (int t = 0; t < SCAND; ++t) {
    int jl = ii[t];
    int j = gbase + jl;
    const f32x4* xj = (const f32x4*)(x + (size_t)j * FDIM);
    double t0 = 0, t1 = 0, t2 = 0, t3 = 0;
#pragma unroll
    for (int f = 0; f < 16; ++f) {
      f32x4 a = xi[f], b = xj[f];
      t0 = fma((double)a[0], (double)b[0], t0);
      t1 = fma((double)a[1], (double)b[1], t1);
      t2 = fma((double)a[2], (double)b[2], t2);
      t3 = fma((double)a[3], (double)b[3], t3);
    }
    double d = sq64i + sq64[j] - 2.0 * ((t0 + t1) + (t2 + t3));
    bool ins = (d < dl[KNN - 1]) || (d == dl[KNN - 1] && jl < il[KNN - 1]);
    if (ins) {
      dl[KNN - 1] = d; il[KNN - 1] = jl;
#pragma unroll
      for (int p = KNN - 1; p >= 1; --p) {
        double a0 = dl[p - 1], a1 = dl[p];
        int b0 = il[p - 1], b1v = il[p];
        bool cc = (a1 < a0) || (a1 == a0 && b1v < b0);
        dl[p - 1] = cc ? a1 : a0; dl[p] = cc ? a0 : a1;
        il[p - 1] = cc ? b1v : b0; il[p] = cc ? b0 : b1v;
      }
    }
  }
#pragma unroll
  for (int q = 0; q < KNN; ++q) {
    md[sub][c_local][q] = dl[q];
    mi[sub][c_local][q] = (unsigned short)il[q];
  }
  __syncthreads();
  if (sub == 0) {
    int pa = 0, pb = 0;
    for (int q = 0; q < KNN; ++q) {
      double da = md[0][c_local][pa]; int ia = mi[0][c_local][pa];
      double db = md[1][c_local][pb]; int ib = mi[1][c_local][pb];
      bool tb = (db < da) || (db == da && ib < ia);
      int iw = tb ? ib : ia;
      pa += !tb; pb += tb;
      int gidx = gbase + iw;
      nbr[(size_t)n * KNN + q] = gidx;
      atomicAdd(&counts[gidx], 1);
    }
  }
}

__global__ void scan_k(const int* __restrict__ counts, int* __restrict__ cursor) {
  __shared__ int part[256];
  int t = threadIdx.x, base = t * 256;
  int s = 0;
  for (int i = 0; i < 256; ++i) s += counts[base + i];
  part[t] = s;
  __syncthreads();
  if (t == 0) {
    int run = 0;
    for (int i = 0; i < 256; ++i) { int v = part[i]; part[i] = run; run += v; }
  }
  __syncthreads();
  int run = part[t];
  for (int i = 0; i < 256; ++i) { int idx = base + i; cursor[idx] = run; run += counts[idx]; }
}

__global__ void scatter_k(const int* __restrict__ nbr, int* __restrict__ cursor,
                          int* __restrict__ srow, int* __restrict__ scol) {
  int e = blockIdx.x * 256 + threadIdx.x;
  int r = nbr[e], c = e >> 4;
  int pos = atomicAdd(&cursor[r], 1);
  srow[pos] = r; scol[pos] = c;
}

// gemm2: fp16 PQ gather with 2-deep register prefetch pipeline; 16KB LDS where the
// fp16 A tile and the fp16 h2 tile alias (barrier-separated); h2 swizzled (row&12)<<3;
// segmented sum by sorted row -> atomicAdd.
__global__ __launch_bounds__(256) void gemm2_k(const _Float16* __restrict__ PQ16,
                                               const int* __restrict__ srow, const int* __restrict__ scol,
                                               const _Float16* __restrict__ w2f,
                                               const float* __restrict__ b2,
                                               float* __restrict__ out) {
  __shared__ __attribute__((aligned(16))) char smem[16384];
  int tid = threadIdx.x, lane = tid & 63, wave = tid >> 6;
  int cg = wave & 1, eg = wave >> 1;
  f16x8 wf[4][4];
#pragma unroll
  for (int ct = 0; ct < 4; ++ct)
#pragma unroll
    for (int ks = 0; ks < 4; ++ks)
      wf[ct][ks] = *(const f16x8*)(w2f + ((((cg * 4 + ct) * 4 + ks) * 64 + lane) * 8));
  float b2r[4];
#pragma unroll
  for (int ct = 0; ct < 4; ++ct) b2r[ct] = b2[cg * 64 + ct * 16 + (lane & 15)];

  int e_in = tid >> 2, qq = tid & 3;
  f16x8 pf[8];
  {
    int e = blockIdx.x * 64 + e_in;
    int row = srow[e], colc = scol[e];
    const f16x8* Pp = (const f16x8*)(PQ16 + (size_t)row * 256 + qq * 32);
    const f16x8* Qp = (const f16x8*)(PQ16 + (size_t)colc * 256 + 128 + qq * 32);
#pragma unroll
    for (int i = 0; i < 4; ++i) { pf[i] = Pp[i]; pf[4 + i] = Qp[i]; }
  }
  for (int tile = blockIdx.x; tile < NT; tile += gridDim.x) {
    int base = tile * 64;
#pragma unroll
    for (int i = 0; i < 4; ++i) {
      f16x8 hv;
#pragma unroll
      for (int e = 0; e < 8; ++e) {
        float sv = (float)pf[i][e] + (float)pf[4 + i][e];
        hv[e] = (_Float16)(sv > 0.f ? sv : 0.f);
      }
      int byteoff = e_in * 256 + ((2 * (qq * 32 + i * 8)) ^ ((e_in & 7) << 4));
      *(f16x8*)(smem + byteoff) = hv;
    }
    int ntile = tile + gridDim.x;
    if (ntile < NT) {
      int e = ntile * 64 + e_in;
      int row = srow[e], colc = scol[e];
      const f16x8* Pp = (const f16x8*)(PQ16 + (size_t)row * 256 + qq * 32);
      const f16x8* Qp = (const f16x8*)(PQ16 + (size_t)colc * 256 + 128 + qq * 32);
#pragma unroll
      for (int i = 0; i < 4; ++i) { pf[i] = Pp[i]; pf[4 + i] = Qp[i]; }
    }
    __syncthreads();
    f32x4 acc[2][4];
#pragma unroll
    for (int rt = 0; rt < 2; ++rt)
#pragma unroll
      for (int ct = 0; ct < 4; ++ct) acc[rt][ct] = (f32x4){0.f, 0.f, 0.f, 0.f};
#pragma unroll
    for (int rt = 0; rt < 2; ++rt) {
      int rowL = eg * 32 + rt * 16 + (lane & 15);
#pragma unroll
      for (int ks = 0; ks < 4; ++ks) {
        int byteoff = rowL * 256 + ((16 * (lane >> 4) + 64 * ks) ^ ((rowL & 7) << 4));
        f16x8 a = *(const f16x8*)(smem + byteoff);
#pragma unroll
        for (int ct = 0; ct < 4; ++ct)
          acc[rt][ct] = __builtin_amdgcn_mfma_f32_16x16x32_f16(a, wf[ct][ks], acc[rt][ct], 0, 0, 0);
      }
    }
    __syncthreads();
#pragma unroll
    for (int rt = 0; rt < 2; ++rt)
#pragma unroll
      for (int ct = 0; ct < 4; ++ct) {
        int col = cg * 64 + ct * 16 + (lane & 15);
#pragma unroll
        for (int r = 0; r < 4; ++r) {
          int row_in = eg * 32 + rt * 16 + (lane >> 4) * 4 + r;
          float v = acc[rt][ct][r] + b2r[ct];
          v = v > 0.f ? v : 0.f;
          int byteoff = row_in * 256 + ((2 * col) ^ ((row_in & 12) << 3));
          *(_Float16*)(smem + byteoff) = (_Float16)v;
        }
      }
    __syncthreads();
    {
      int col = tid & 127, estart = (tid >> 7) * 32;
      float a = 0.f;
      int prev = srow[base + estart];
#pragma unroll 8
      for (int e2 = estart; e2 < estart + 32; ++e2) {
        int r2 = srow[base + e2];
        if (r2 != prev) { atomicAdd(out + (size_t)prev * 128 + col, a); a = 0.f; prev = r2; }
        int byteoff = e2 * 256 + ((2 * col) ^ ((e2 & 12) << 3));
        a += (float)*(const _Float16*)(smem + byteoff);
      }
      atomicAdd(out + (size_t)prev * 128 + col, a);
    }
    __syncthreads();
  }
}

__global__ void final_k(float* __restrict__ out, const int* __restrict__ counts) {
  int idx = blockIdx.x * 256 + threadIdx.x;
  int n = idx >> 7;
  int c = counts[n];
  c = c > 0 ? c : 1;
  out[idx] = out[idx] / (float)c;
}

extern "C" void kernel_launch(void* const* d_in, const int* in_sizes, int n_in,
                              void* d_out, int out_size, void* d_ws, size_t ws_size,
                              hipStream_t stream) {
  const float* x = (const float*)d_in[0];
  const float* W1 = (const float*)d_in[2];
  const float* b1 = (const float*)d_in[3];
  const float* W2 = (const float*)d_in[4];
  const float* b2 = (const float*)d_in[5];
  float* out = (float*)d_out;
  char* ws = (char*)d_ws;

  // PQ16 region (32 MB) is aliased by KNN-phase buffers (candi/xf): all KNN kernels run
  // BEFORE prep_pq_k writes PQ16, so lifetimes are disjoint (stream-ordered).
  _Float16* PQ16 = (_Float16*)(ws + 0);                    // 33,554,432 B
  unsigned short* candi = (unsigned short*)(ws + 0);       //  5,242,880 B (alias PQ16)
  _Float16* xf = (_Float16*)(ws + 16777216);               //  8,388,608 B (alias PQ16)
  float* sq = (float*)(ws + 67108864);                     //    262,144 B
  int* nbr = (int*)(ws + 67371008);                        //  4,194,304 B
  int* counts = (int*)(ws + 71565312);                     //    262,144 B
  int* cursor = (int*)(ws + 71827456);                     //    262,144 B
  int* srow = (int*)(ws + 72089600);                       //  4,194,304 B
  int* scol = (int*)(ws + 76283904);                       //  4,194,304 B
  _Float16* w2f = (_Float16*)(ws + 80478208);              //     32,768 B
  double* sq64 = (double*)(ws + 80543744);                 //    524,288 B  (end 81,068,032)

  hipMemsetAsync(d_out, 0, (size_t)out_size * sizeof(float), stream);
  hipMemsetAsync(counts, 0, (size_t)N_NODES * sizeof(int), stream);
  prep_weights_k<<<1, 256, 0, stream>>>(W2, w2f);
  prep_node_k<<<N_NODES / 256, 256, 0, stream>>>(x, sq, sq64, xf);
  knn1_k<<<N_NODES / 128, 256, 0, stream>>>(xf, sq, candi);
  knn2_k<<<N_NODES / 128, 256, 0, stream>>>(x, sq64, candi, nbr, counts);
  scan_k<<<1, 256, 0, stream>>>(counts, cursor);
  scatter_k<<<NEDGE / 256, 256, 0, stream>>>(nbr, cursor, srow, scol);
  prep_pq_k<<<N_NODES / 16, 256, 0, stream>>>(x, W1, b1, PQ16);
  gemm2_k<<<2048, 256, 0, stream>>>(PQ16, srow, scol, w2f, b2, out);
  final_k<<<(N_NODES * HDIM) / 256, 256, 0, stream>>>(out, counts);
}

// Round 13
// 745.488 us; speedup vs baseline: 1.8245x; 1.0202x over previous
//
#include <hip/hip_runtime.h>

typedef __attribute__((ext_vector_type(4))) float f32x4;
typedef __attribute__((ext_vector_type(4))) unsigned int u32x4;
typedef __attribute__((ext_vector_type(8))) short s16x8;
typedef __attribute__((ext_vector_type(8))) _Float16 f16x8;

#define N_NODES 65536
#define GNPG 1024
#define FDIM 64
#define HDIM 128
#define KNN 16
#define JT 64      // knn j-tile
#define DSTR 68    // knn key LDS row stride (u32)
#define SCAND 20   // per-subset candidate list (2 subsets/center)
#define STKC 6     // per-lane survivor stack depth (u32 keys)
#define NEDGE (N_NODES * KNN)
#define ETILE 128
#define NT (NEDGE / ETILE)

// Build MFMA B-fragment-ordered fp16 copy of W2 (128x128).
__global__ void prep_weights_k(const float* __restrict__ W2, _Float16* __restrict__ w2f) {
  int tid = threadIdx.x;
  for (int idx = tid; idx < 8 * 4 * 64 * 8; idx += 256) {
    int j = idx & 7, l = (idx >> 3) & 63, ks = (idx >> 9) & 3, ct = idx >> 11;
    int k = 8 * (l >> 4) + j + 32 * ks, col = ct * 16 + (l & 15);
    w2f[idx] = (_Float16)W2[k * 128 + col];
  }
}

// Per-node precompute, coalesced: 4 threads/node (64B/lane contiguous). f64 norm via
// 4-lane shfl reduce; fp16 copy of x written 32B/lane contiguous.
__global__ void prep_node_k(const float* __restrict__ x, float* __restrict__ sq,
                            double* __restrict__ sq64, _Float16* __restrict__ xf) {
  int t = blockIdx.x * 256 + threadIdx.x;
  int n = t >> 2, q = t & 3;
  const f32x4* xp = (const f32x4*)(x + (size_t)n * FDIM + q * 16);
  double s = 0;
  f16x8 h0, h1;
#pragma unroll
  for (int c8 = 0; c8 < 2; ++c8) {
    f32x4 a = xp[2 * c8], b = xp[2 * c8 + 1];
    f16x8 h;
#pragma unroll
    for (int e = 0; e < 4; ++e) {
      h[e] = (_Float16)a[e];
      h[4 + e] = (_Float16)b[e];
      s = fma((double)a[e], (double)a[e], s);
      s = fma((double)b[e], (double)b[e], s);
    }
    if (c8 == 0) h0 = h; else h1 = h;
  }
  *(f16x8*)(xf + (size_t)n * FDIM + q * 16) = h0;
  *(f16x8*)(xf + (size_t)n * FDIM + q * 16 + 8) = h1;
  s += __shfl_xor(s, 1);
  s += __shfl_xor(s, 2);
  if (q == 0) { sq64[n] = s; sq[n] = (float)s; }
}

// fp32 GEMM1 -> fp16 store, 64 nodes/block (amortized Wc staging; xL pad stride 65).
__global__ __launch_bounds__(256) void prep_pq_k(const float* __restrict__ x,
                                                 const float* __restrict__ W1,
                                                 const float* __restrict__ b1,
                                                 _Float16* __restrict__ PQ16) {
  __shared__ float WcL[64 * 256];   // 64KB
  __shared__ float xL[64 * 65];     // 16.25KB
  int tid = threadIdx.x;
  for (int i = tid; i < 64 * 256; i += 256) {
    int k = i >> 8, c = i & 255;
    WcL[i] = (c < 128) ? (W1[k * 128 + c] - W1[(k + 64) * 128 + c])
                       : W1[(k + 64) * 128 + (c - 128)];
  }
  int nbase = blockIdx.x * 64;
  for (int i = tid; i < 64 * 64; i += 256) xL[(i >> 6) * 65 + (i & 63)] = x[(size_t)nbase * 64 + i];
  __syncthreads();
  int nl0 = tid >> 4, c0 = tid & 15;
#pragma unroll 1
  for (int p = 0; p < 4; ++p) {
    int nl = p * 16 + nl0;
    float acc[16];
#pragma unroll
    for (int j = 0; j < 16; ++j) acc[j] = 0.f;
    for (int k = 0; k < 64; ++k) {
      float xk = xL[nl * 65 + k];
      const float* wr = WcL + k * 256 + c0;
#pragma unroll
      for (int j = 0; j < 16; ++j) acc[j] = fmaf(xk, wr[16 * j], acc[j]);
    }
#pragma unroll
    for (int j = 0; j < 16; ++j) {
      int c = c0 + 16 * j;
      float b = (c >= 128) ? b1[c - 128] : 0.f;
      PQ16[(size_t)(nbase + nl) * 256 + c] = (_Float16)(acc[j] + b);
    }
  }
}

// KNN stage 1 (fp16 MFMA + packed u32 keys + stack filter). Unchanged from r12.
__global__ __launch_bounds__(256) void knn1_k(const _Float16* __restrict__ xf,
                                              const float* __restrict__ sq,
                                              unsigned short* __restrict__ candi) {
  __shared__ float sq_l[GNPG];
  __shared__ __attribute__((aligned(16))) _Float16 bfL[512 * 8];
  __shared__ __attribute__((aligned(16))) unsigned keyL[128 * DSTR];
  __shared__ __attribute__((aligned(16))) unsigned stk[STKC * 256];
  int tid = threadIdx.x, lane = tid & 63, wave = tid >> 6;
  int g = blockIdx.x >> 3;
  int rb = (blockIdx.x & 7) * 128;
  const _Float16* xfg = xf + (size_t)g * GNPG * FDIM;
  for (int i = tid; i < GNPG; i += 256) sq_l[i] = sq[g * GNPG + i];
  f16x8 af[2][2];
#pragma unroll
  for (int rt = 0; rt < 2; ++rt)
#pragma unroll
    for (int ks = 0; ks < 2; ++ks) {
      size_t off = (size_t)(rb + wave * 32 + rt * 16 + (lane & 15)) * FDIM + (lane >> 4) * 8 + 32 * ks;
      af[rt][ks] = *(const f16x8*)(xfg + off);
    }
  unsigned dl[SCAND];
#pragma unroll
  for (int q = 0; q < SCAND; ++q) dl[q] = 0xFFFFFFFFu;
  int c = tid >> 1, sub = tid & 1;
  int sp = 0;
  for (int jt = 0; jt < GNPG / JT; ++jt) {
#pragma unroll
    for (int s2 = tid; s2 < 512; s2 += 256) {
      int ct = s2 >> 7, ks = (s2 >> 6) & 1, l = s2 & 63;
      size_t goff = (size_t)(jt * JT + ct * 16 + (l & 15)) * FDIM + (l >> 4) * 8 + 32 * ks;
      *(f16x8*)(bfL + s2 * 8) = *(const f16x8*)(xfg + goff);
    }
    __syncthreads();
    f32x4 acc[2][4];
#pragma unroll
    for (int rt = 0; rt < 2; ++rt)
#pragma unroll
      for (int ct = 0; ct < 4; ++ct) acc[rt][ct] = (f32x4){0.f, 0.f, 0.f, 0.f};
#pragma unroll
    for (int ks = 0; ks < 2; ++ks)
#pragma unroll
      for (int ct = 0; ct < 4; ++ct) {
        f16x8 bfr = *(const f16x8*)(bfL + ((ct * 2 + ks) * 64 + lane) * 8);
#pragma unroll
        for (int rt = 0; rt < 2; ++rt)
          acc[rt][ct] = __builtin_amdgcn_mfma_f32_16x16x32_f16(af[rt][ks], bfr, acc[rt][ct], 0, 0, 0);
      }
#pragma unroll
    for (int rt = 0; rt < 2; ++rt)
#pragma unroll
      for (int ct = 0; ct < 4; ++ct) {
        int coltl = ct * 16 + (lane & 15);
        int jlg = jt * JT + coltl;
        float sqj = sq_l[jlg];
#pragma unroll
        for (int r = 0; r < 4; ++r) {
          int row = wave * 32 + rt * 16 + (lane >> 4) * 4 + r;
          float d = sq_l[rb + row] + sqj - 2.f * acc[rt][ct][r];
          unsigned b = __float_as_uint(d);
          b ^= (unsigned)(((int)b >> 31) | 0x80000000);
          unsigned key = (b & 0xFFFFFC00u) | (unsigned)jlg;
          if (rb + row == jlg) key = 0xFFFFFFFFu;
          keyL[row * DSTR + coltl] = key;
        }
      }
    __syncthreads();
    const unsigned* kp = keyL + c * DSTR + sub * 32;
#pragma unroll 2
    for (int i = 0; i < 8; ++i) {
      if (__any(sp > STKC - 4)) {
        while (__any(sp > 0)) {
          if (sp > 0) {
            --sp;
            unsigned k = stk[sp * 256 + tid];
            if (k < dl[SCAND - 1]) {
              dl[SCAND - 1] = k;
#pragma unroll
              for (int p = SCAND - 1; p >= 1; --p) {
                unsigned mn = min(dl[p - 1], dl[p]);
                unsigned mx = max(dl[p - 1], dl[p]);
                dl[p - 1] = mn; dl[p] = mx;
              }
            }
          }
        }
      }
      u32x4 v = *(const u32x4*)(kp + i * 4);
#pragma unroll
      for (int e = 0; e < 4; ++e) {
        stk[sp * 256 + tid] = v[e];
        sp += (v[e] < dl[SCAND - 1]) ? 1 : 0;
      }
    }
  }
  while (__any(sp > 0)) {
    if (sp > 0) {
      --sp;
      unsigned k = stk[sp * 256 + tid];
      if (k < dl[SCAND - 1]) {
        dl[SCAND - 1] = k;
#pragma unroll
        for (int p = SCAND - 1; p >= 1; --p) {
          unsigned mn = min(dl[p - 1], dl[p]);
          unsigned mx = max(dl[p - 1], dl[p]);
          dl[p - 1] = mn; dl[p] = mx;
        }
      }
    }
  }
  int nglob = g * GNPG + rb + c;
  unsigned short* ii = candi + (size_t)nglob * (2 * SCAND) + sub * SCAND;
#pragma unroll
  for (int q = 0; q < SCAND; ++q) ii[q] = (unsigned short)(dl[q] & 1023u);
}

// KNN stage 2: unchanged from r12 (2 threads/center, f64 rescore + 2-pointer merge).
__global__ __launch_bounds__(256) void knn2_k(const float* __restrict__ x,
                                              const double* __restrict__ sq64,
                                              const unsigned short* __restrict__ candi,
                                              int* __restrict__ nbr, int* __restrict__ counts) {
  __shared__ double md[2][128][17];
  __shared__ unsigned short mi[2][128][17];
  int tid = threadIdx.x, c_local = tid >> 1, sub = tid & 1;
  int n = blockIdx.x * 128 + c_local;
  int gbase = n & ~(GNPG - 1);
  f32x4 xi[16];
  const f32x4* xp = (const f32x4*)(x + (size_t)n * FDIM);
#pragma unroll
  for (int f = 0; f < 16; ++f) xi[f] = xp[f];
  double sq64i = sq64[n];
  double dl[KNN]; int il[KNN];
#pragma unroll
  for (int q = 0; q < KNN; ++q) { dl[q] = 1.0e300; il[q] = 0x7FFFFFFF; }
  const unsigned short* ii = candi + (size_t)n * (2 * SCAND) + sub * SCAND;
#pragma unroll 1
  for (int t = 0; t < SCAND; ++t) {
    int jl = ii[t];
    int j = gbase + jl;
    const f32x4* xj = (const f32x4*)(x + (size_t)j * FDIM);
    double t0 = 0, t1 = 0, t2 = 0, t3 = 0;
#pragma unroll
    for (int f = 0; f < 16; ++f) {
      f32x4 a = xi[f], b = xj[f];
      t0 = fma((double)a[0], (double)b[0], t0);
      t1 = fma((double)a[1], (double)b[1], t1);
      t2 = fma((double)a[2], (double)b[2], t2);
      t3 = fma((double)a[3], (double)b[3], t3);
    }
    double d = sq64i + sq64[j] - 2.0 * ((t0 + t1) + (t2 + t3));
    bool ins = (d < dl[KNN - 1]) || (d == dl[KNN - 1] && jl < il[KNN - 1]);
    if (ins) {
      dl[KNN - 1] = d; il[KNN - 1] = jl;
#pragma unroll
      for (int p = KNN - 1; p >= 1; --p) {
        double a0 = dl[p - 1], a1 = dl[p];
        int b0 = il[p - 1], b1v = il[p];
        bool cc = (a1 < a0) || (a1 == a0 && b1v < b0);
        dl[p - 1] = cc ? a1 : a0; dl[p] = cc ? a0 : a1;
        il[p - 1] = cc ? b1v : b0; il[p] = cc ? b0 : b1v;
      }
    }
  }
#pragma unroll
  for (int q = 0; q < KNN; ++q) {
    md[sub][c_local][q] = dl[q];
    mi[sub][c_local][q] = (unsigned short)il[q];
  }
  __syncthreads();
  if (sub == 0) {
    int pa = 0, pb = 0;
    for (int q = 0; q < KNN; ++q) {
      double da = md[0][c_local][pa]; int ia = mi[0][c_local][pa];
      double db = md[1][c_local][pb]; int ib = mi[1][c_local][pb];
      bool tb = (db < da) || (db == da && ib < ia);
      int iw = tb ? ib : ia;
      pa += !tb; pb += tb;
      int gidx = gbase + iw;
      nbr[(size_t)n * KNN + q] = gidx;
      atomicAdd(&counts[gidx], 1);
    }
  }
}

// Block-wide scan: 1024 threads x 64 counts (int4 loads), shfl wave-scan + wave partials.
__global__ void scan_k(const int* __restrict__ counts, int* __restrict__ cursor) {
  __shared__ int wsum[16];
  int t = threadIdx.x;
  int base = t * 64;
  const int4* cp = (const int4*)(counts + base);
  int s = 0;
#pragma unroll
  for (int i = 0; i < 16; ++i) { int4 v = cp[i]; s += v.x + v.y + v.z + v.w; }
  int lane = t & 63, wv = t >> 6;
  int pre = s;
#pragma unroll
  for (int ofs = 1; ofs < 64; ofs <<= 1) {
    int o = __shfl_up(pre, ofs);
    if (lane >= ofs) pre += o;
  }
  if (lane == 63) wsum[wv] = pre;
  __syncthreads();
  if (t == 0) {
    int run = 0;
#pragma unroll
    for (int i = 0; i < 16; ++i) { int v = wsum[i]; wsum[i] = run; run += v; }
  }
  __syncthreads();
  int run = wsum[wv] + pre - s;
#pragma unroll
  for (int i = 0; i < 16; ++i) {
    int4 v = cp[i];
    cursor[base + 4 * i] = run; run += v.x;
    cursor[base + 4 * i + 1] = run; run += v.y;
    cursor[base + 4 * i + 2] = run; run += v.z;
    cursor[base + 4 * i + 3] = run; run += v.w;
  }
}

__global__ void scatter_k(const int* __restrict__ nbr, int* __restrict__ cursor,
                          int* __restrict__ srow, int* __restrict__ scol) {
  int e = blockIdx.x * 256 + threadIdx.x;
  int r = nbr[e], c = e >> 4;
  int pos = atomicAdd(&cursor[r], 1);
  srow[pos] = r; scol[pos] = c;
}

// gemm2: 128-edge tiles, 512 threads (8 waves: 4 row-groups x 2 col-groups), fp16 PQ
// gather with 2-deep register prefetch; 32KB LDS (A fp16 aliases h2 fp16, barrier-sep);
// segmented sum by sorted row -> atomicAdd.
__global__ __launch_bounds__(512) void gemm2_k(const _Float16* __restrict__ PQ16,
                                               const int* __restrict__ srow, const int* __restrict__ scol,
                                               const _Float16* __restrict__ w2f,
                                               const float* __restrict__ b2,
                                               float* __restrict__ out) {
  __shared__ __attribute__((aligned(16))) char smem[32768];
  int tid = threadIdx.x, lane = tid & 63, wave = tid >> 6;
  int cg = wave & 1, eg = wave >> 1;   // eg 0..3 -> rows eg*32..+32
  f16x8 wf[4][4];
#pragma unroll
  for (int ct = 0; ct < 4; ++ct)
#pragma unroll
    for (int ks = 0; ks < 4; ++ks)
      wf[ct][ks] = *(const f16x8*)(w2f + ((((cg * 4 + ct) * 4 + ks) * 64 + lane) * 8));
  float b2r[4];
#pragma unroll
  for (int ct = 0; ct < 4; ++ct) b2r[ct] = b2[cg * 64 + ct * 16 + (lane & 15)];

  int e_in = tid >> 2, qq = tid & 3;   // e_in 0..127
  f16x8 pf[8];
  {
    int e = blockIdx.x * ETILE + e_in;
    int row = srow[e], colc = scol[e];
    const f16x8* Pp = (const f16x8*)(PQ16 + (size_t)row * 256 + qq * 32);
    const f16x8* Qp = (const f16x8*)(PQ16 + (size_t)colc * 256 + 128 + qq * 32);
#pragma unroll
    for (int i = 0; i < 4; ++i) { pf[i] = Pp[i]; pf[4 + i] = Qp[i]; }
  }
  for (int tile = blockIdx.x; tile < NT; tile += gridDim.x) {
    int base = tile * ETILE;
#pragma unroll
    for (int i = 0; i < 4; ++i) {
      f16x8 hv;
#pragma unroll
      for (int e = 0; e < 8; ++e) {
        float sv = (float)pf[i][e] + (float)pf[4 + i][e];
        hv[e] = (_Float16)(sv > 0.f ? sv : 0.f);
      }
      int byteoff = e_in * 256 + ((2 * (qq * 32 + i * 8)) ^ ((e_in & 7) << 4));
      *(f16x8*)(smem + byteoff) = hv;
    }
    int ntile = tile + gridDim.x;
    if (ntile < NT) {
      int e = ntile * ETILE + e_in;
      int row = srow[e], colc = scol[e];
      const f16x8* Pp = (const f16x8*)(PQ16 + (size_t)row * 256 + qq * 32);
      const f16x8* Qp = (const f16x8*)(PQ16 + (size_t)colc * 256 + 128 + qq * 32);
#pragma unroll
      for (int i = 0; i < 4; ++i) { pf[i] = Pp[i]; pf[4 + i] = Qp[i]; }
    }
    __syncthreads();
    f32x4 acc[2][4];
#pragma unroll
    for (int rt = 0; rt < 2; ++rt)
#pragma unroll
      for (int ct = 0; ct < 4; ++ct) acc[rt][ct] = (f32x4){0.f, 0.f, 0.f, 0.f};
#pragma unroll
    for (int rt = 0; rt < 2; ++rt) {
      int rowL = eg * 32 + rt * 16 + (lane & 15);
#pragma unroll
      for (int ks = 0; ks < 4; ++ks) {
        int byteoff = rowL * 256 + ((16 * (lane >> 4) + 64 * ks) ^ ((rowL & 7) << 4));
        f16x8 a = *(const f16x8*)(smem + byteoff);
#pragma unroll
        for (int ct = 0; ct < 4; ++ct)
          acc[rt][ct] = __builtin_amdgcn_mfma_f32_16x16x32_f16(a, wf[ct][ks], acc[rt][ct], 0, 0, 0);
      }
    }
    __syncthreads();
#pragma unroll
    for (int rt = 0; rt < 2; ++rt)
#pragma unroll
      for (int ct = 0; ct < 4; ++ct) {
        int col = cg * 64 + ct * 16 + (lane & 15);
#pragma unroll
        for (int r = 0; r < 4; ++r) {
          int row_in = eg * 32 + rt * 16 + (lane >> 4) * 4 + r;
          float v = acc[rt][ct][r] + b2r[ct];
          v = v > 0.f ? v : 0.f;
          int byteoff = row_in * 256 + ((2 * col) ^ ((row_in & 12) << 3));
          *(_Float16*)(smem + byteoff) = (_Float16)v;
        }
      }
    __syncthreads();
    {
      int col = tid & 127, estart = (tid >> 7) * 32;
      float a = 0.f;
      int prev = srow[base + estart];
#pragma unroll 8
      for (int e2 = estart; e2 < estart + 32; ++e2) {
        int r2 = srow[base + e2];
        if (r2 != prev) { atomicAdd(out + (size_t)prev * 128 + col, a); a = 0.f; prev = r2; }
        int byteoff = e2 * 256 + ((2 * col) ^ ((e2 & 12) << 3));
        a += (float)*(const _Float16*)(smem + byteoff);
      }
      atomicAdd(out + (size_t)prev * 128 + col, a);
    }
    __syncthreads();
  }
}

__global__ void final_k(float* __restrict__ out, const int* __restrict__ counts) {
  for (int i = blockIdx.x * 256 + threadIdx.x; i < N_NODES * 32; i += gridDim.x * 256) {
    f32x4 v = ((f32x4*)out)[i];
    int n = i >> 5;
    int c = counts[n];
    float inv = 1.0f / (float)(c > 0 ? c : 1);
    v[0] *= inv; v[1] *= inv; v[2] *= inv; v[3] *= inv;
    ((f32x4*)out)[i] = v;
  }
}

extern "C" void kernel_launch(void* const* d_in, const int* in_sizes, int n_in,
                              void* d_out, int out_size, void* d_ws, size_t ws_size,
                              hipStream_t stream) {
  const float* x = (const float*)d_in[0];
  const float* W1 = (const float*)d_in[2];
  const float* b1 = (const float*)d_in[3];
  const float* W2 = (const float*)d_in[4];
  const float* b2 = (const float*)d_in[5];
  float* out = (float*)d_out;
  char* ws = (char*)d_ws;

  // PQ16 region (32 MB) is aliased by KNN-phase buffers (candi/xf): all KNN kernels run
  // BEFORE prep_pq_k writes PQ16, so lifetimes are disjoint (stream-ordered).
  _Float16* PQ16 = (_Float16*)(ws + 0);                    // 33,554,432 B
  unsigned short* candi = (unsigned short*)(ws + 0);       //  5,242,880 B (alias PQ16)
  _Float16* xf = (_Float16*)(ws + 16777216);               //  8,388,608 B (alias PQ16)
  float* sq = (float*)(ws + 67108864);                     //    262,144 B
  int* nbr = (int*)(ws + 67371008);                        //  4,194,304 B
  int* counts = (int*)(ws + 71565312);                     //    262,144 B
  int* cursor = (int*)(ws + 71827456);                     //    262,144 B
  int* srow = (int*)(ws + 72089600);                       //  4,194,304 B
  int* scol = (int*)(ws + 76283904);                       //  4,194,304 B
  _Float16* w2f = (_Float16*)(ws + 80478208);              //     32,768 B
  double* sq64 = (double*)(ws + 80543744);                 //    524,288 B  (end 81,068,032)

  hipMemsetAsync(d_out, 0, (size_t)out_size * sizeof(float), stream);
  hipMemsetAsync(counts, 0, (size_t)N_NODES * sizeof(int), stream);
  prep_weights_k<<<1, 256, 0, stream>>>(W2, w2f);
  prep_node_k<<<N_NODES * 4 / 256, 256, 0, stream>>>(x, sq, sq64, xf);
  knn1_k<<<N_NODES / 128, 256, 0, stream>>>(xf, sq, candi);
  knn2_k<<<N_NODES / 128, 256, 0, stream>>>(x, sq64, candi, nbr, counts);
  scan_k<<<1, 1024, 0, stream>>>(counts, cursor);
  scatter_k<<<NEDGE / 256, 256, 0, stream>>>(nbr, cursor, srow, scol);
  prep_pq_k<<<N_NODES / 64, 256, 0, stream>>>(x, W1, b1, PQ16);
  gemm2_k<<<1024, 512, 0, stream>>>(PQ16, srow, scol, w2f, b2, out);
  final_k<<<2048, 256, 0, stream>>>(out, counts);
}